// Round 5
// baseline (1410.474 us; speedup 1.0000x reference)
//
#include <hip/hip_runtime.h>
#include <stdint.h>

#define N_NODES 100000
#define N_EDGES 1600000
#define CH 128
#define EDGE_DIM 16
#define KUPD (2 * CH)         // 256
#define NPW 8                 // nodes per wave (gemm/upd)

__device__ __forceinline__ float bf2f(ushort u) {
  union { uint i; float f; } c; c.i = ((uint)u) << 16; return c.f;
}
__device__ __forceinline__ ushort f2bf(float f) {
  union { float f; uint i; } c; c.f = f;
  return (ushort)((c.i + 0x7FFFu + ((c.i >> 16) & 1u)) >> 16);
}
// dtype-dispatched paired load: elements (2*pi, 2*pi+1)
__device__ __forceinline__ float2 ld2(const void* p, int f32, size_t pi) {
  if (f32) return ((const float2*)p)[pi];
  uint u = ((const uint*)p)[pi];
  return make_float2(bf2f((ushort)(u & 0xFFFF)), bf2f((ushort)(u >> 16)));
}
// dtype-dispatched quad load: elements (4*qi .. 4*qi+3)
__device__ __forceinline__ float4 ld4(const void* p, int f32, size_t qi) {
  if (f32) return ((const float4*)p)[qi];
  uint2 u = ((const uint2*)p)[qi];
  float4 r;
  r.x = bf2f((ushort)(u.x & 0xFFFF)); r.y = bf2f((ushort)(u.x >> 16));
  r.z = bf2f((ushort)(u.y & 0xFFFF)); r.w = bf2f((ushort)(u.y >> 16));
  return r;
}
// FAST=1: compile-time f32 direct load (bit-identical to ld2/ld4's f32 branch).
template <int FAST>
__device__ __forceinline__ float2 ld2t(const void* p, int f32, size_t pi) {
  if (FAST) return ((const float2*)p)[pi];
  return ld2(p, f32, pi);
}
template <int FAST>
__device__ __forceinline__ float4 ld4t(const void* p, int f32, size_t qi) {
  if (FAST) return ((const float4*)p)[qi];
  return ld4(p, f32, qi);
}
// x_sel: 0 = force bf16, 1 = use detected x flag, 2 = force f32
__device__ __forceinline__ int resolve_f32(int x_sel, const int* flags) {
  return (x_sel == 2) ? 1 : (x_sel == 1 ? flags[1] : 0);
}

// ---------------------------------------------------------------- runtime layout/dtype detection
// flags[0]=1 -> edge_index int32 [2,E]. flags[1..3]=1 -> x / edge_attr / weights are f32.
__global__ __launch_bounds__(256) void detect_kernel(const int* __restrict__ ei,
                                                     const ushort* __restrict__ xu,
                                                     const ushort* __restrict__ eau,
                                                     const ushort* __restrict__ wu,
                                                     int* __restrict__ flags) {
  int any = 0, fx = 0, fe = 0, fw = 0;
  for (int i = threadIdx.x; i < 4096; i += 256) any |= ei[2 * i + 1];
  for (int i = threadIdx.x; i < 16384; i += 256) {
    fx |= (((xu[2 * i] >> 7) & 0xFF) == 0xFF);
    fe |= (((eau[2 * i] >> 7) & 0xFF) == 0xFF);
  }
  for (int i = threadIdx.x; i < 8192; i += 256) {
    fw |= (((wu[2 * i] >> 7) & 0xFF) == 0xFF);
  }
  if (any) atomicOr(flags + 0, 1);
  if (fx)  atomicOr(flags + 1, 1);
  if (fe)  atomicOr(flags + 2, 1);
  if (fw)  atomicOr(flags + 3, 1);
}

__device__ __forceinline__ void load_edge(const int* __restrict__ ei, int i32, int e,
                                          int& s, int& d) {
  if (i32) { s = ei[e]; d = ei[N_EDGES + e]; }
  else     { s = ei[2 * e]; d = ei[2 * N_EDGES + 2 * e]; }
  s = min(max(s, 0), N_NODES - 1);
  d = min(max(d, 0), N_NODES - 1);
}

// ---------------------------------------------------------------- degree count (dst only: half the read)
__global__ __launch_bounds__(256) void count_kernel(const int* __restrict__ ei,
                                                    const int* __restrict__ flags,
                                                    int* __restrict__ cnt) {
  int e = blockIdx.x * 256 + threadIdx.x;
  if (e >= N_EDGES) return;
  int d = flags[0] ? ei[N_EDGES + e] : ei[2 * N_EDGES + 2 * e];
  d = min(max(d, 0), N_NODES - 1);
  atomicAdd(&cnt[d], 1);
}

// ---------------------------------------------------------------- exclusive prefix scan of cnt -> rowptr
__global__ __launch_bounds__(1024) void scan_kernel(const int* __restrict__ cnt,
                                                    int* __restrict__ rowptr) {
  __shared__ int part[1024];
  const int t = threadIdx.x;
  const int CHUNK = (N_NODES + 1023) / 1024;  // 98
  int base = t * CHUNK;
  int lim = min(base + CHUNK, N_NODES);
  int s = 0;
  for (int i = base; i < lim; ++i) s += cnt[i];
  part[t] = s;
  __syncthreads();
  for (int off = 1; off < 1024; off <<= 1) {
    int v = (t >= off) ? part[t - off] : 0;
    __syncthreads();
    part[t] += v;
    __syncthreads();
  }
  int excl = (t == 0) ? 0 : part[t - 1];
  for (int i = base; i < lim; ++i) { rowptr[i] = excl; excl += cnt[i]; }
  if (t == 1023) rowptr[N_NODES] = part[1023];
}

// ---------------------------------------------------------------- CSR scatter: {src, eid} sorted by dst
__global__ __launch_bounds__(256) void scatter_kernel(const int* __restrict__ ei,
                                                      const int* __restrict__ flags,
                                                      const int* __restrict__ rowptr,
                                                      int* __restrict__ fill,
                                                      int2* __restrict__ sev) {
  int e = blockIdx.x * 256 + threadIdx.x;
  if (e >= N_EDGES) return;
  int s, d;
  load_edge(ei, flags[0], e, s, d);
  int pos = atomicAdd(&fill[d], 1);
  sev[rowptr[d] + pos] = make_int2(s, e);
}

// ---------------------------------------------------------------- node-level GEMM: y = x @ W[0:128] + b -> packed bf16
// FAST=1 path: branch-free float2 loads (the per-load uniform dtype branch was
// in every k-iteration of R4's loop). One top-level uniform branch instead.
template <int FAST>
__device__ __forceinline__ void gemm_body(const void* __restrict__ x, int xf,
                                          const void* __restrict__ W, int wf,
                                          const void* __restrict__ b,
                                          uint* __restrict__ ybf,
                                          int wave, int lane, float (*xs)[CH]) {
  const int n0 = (blockIdx.x * 4 + wave) * NPW;  // N = 32*gridDim exactly
#pragma unroll
  for (int r = 0; r < NPW; ++r) {
    float2 a = ld2t<FAST>(x, xf, (size_t)(n0 + r) * 64 + lane);
    xs[r][2 * lane]     = a.x;
    xs[r][2 * lane + 1] = a.y;
  }
  __syncthreads();

  float acc0[NPW], acc1[NPW];
#pragma unroll
  for (int r = 0; r < NPW; ++r) { acc0[r] = 0.f; acc1[r] = 0.f; }

#pragma unroll 4
  for (int k = 0; k < CH; k += 2) {
    float2 w0 = ld2t<FAST>(W, wf, (size_t)k * 64 + lane);
    float2 w1 = ld2t<FAST>(W, wf, (size_t)(k + 1) * 64 + lane);
#pragma unroll
    for (int r = 0; r < NPW; ++r) {
      float2 a = *(const float2*)&xs[r][k];
      acc0[r] += a.x * w0.x;
      acc1[r] += a.x * w0.y;
      acc0[r] += a.y * w1.x;
      acc1[r] += a.y * w1.y;
    }
  }

  float2 bb = ld2t<FAST>(b, wf, lane);
#pragma unroll
  for (int r = 0; r < NPW; ++r) {
    uint pk = (uint)f2bf(acc0[r] + bb.x) | ((uint)f2bf(acc1[r] + bb.y) << 16);
    ybf[(uint)(n0 + r) * 64u + (uint)lane] = pk;
  }
}

__global__ __launch_bounds__(256) void gemm_node(const void* __restrict__ x, int x_sel,
                                                 const void* __restrict__ W,
                                                 const void* __restrict__ b,
                                                 const int* __restrict__ flags,
                                                 uint* __restrict__ ybf) {
  __shared__ float xs[4][NPW][CH];  // 16 KB
  const int wave = threadIdx.x >> 6;
  const int lane = threadIdx.x & 63;
  const int xf = resolve_f32(x_sel, flags), wf = flags[3];
  if (xf & wf) gemm_body<1>(x, xf, W, wf, b, ybf, wave, lane, xs[wave]);
  else         gemm_body<0>(x, xf, W, wf, b, ybf, wave, lane, xs[wave]);
}

// ---------------------------------------------------------------- CSR aggregation:
// One wave per dst node, 4-edge batches. Loop bounds readfirstlane'd -> fully
// SCALAR loop control (s_cmp/s_cbranch, no exec-mask churn), and sev/ea
// addresses become provably uniform (scalar-load path). y gathers use 32-bit
// offsets (ybf spans 25.6MB). Direct fmac chain (ascending k, same order as R4).
template <int FAST>
__device__ __forceinline__ void agg_body(const uint* __restrict__ ybf,
                                         const void* __restrict__ ea,
                                         const void* __restrict__ W,
                                         const int* __restrict__ rowptr,
                                         const int2* __restrict__ sev,
                                         int ef, int wf,
                                         float* __restrict__ agg,
                                         int wave, int lane) {
  float wex[EDGE_DIM], wey[EDGE_DIM];
#pragma unroll
  for (int k = 0; k < EDGE_DIM; ++k) {
    float2 wv = ld2t<FAST>(W, wf, (size_t)(CH + k) * 64 + lane);
    wex[k] = wv.x; wey[k] = wv.y;
  }

  const int n = blockIdx.x * 4 + wave;  // grid = N/4 exactly; uniform within wave
  const int beg = __builtin_amdgcn_readfirstlane(rowptr[n]);
  const int end = __builtin_amdgcn_readfirstlane(rowptr[n + 1]);
  float acc0 = 0.f, acc1 = 0.f;

  auto edge = [&](uint yu, float4 q0, float4 q1, float4 q2, float4 q3) {
    float z0 = q0.x * wex[0],  z1 = q0.x * wey[0];
    z0 += q0.y * wex[1];  z1 += q0.y * wey[1];
    z0 += q0.z * wex[2];  z1 += q0.z * wey[2];
    z0 += q0.w * wex[3];  z1 += q0.w * wey[3];
    z0 += q1.x * wex[4];  z1 += q1.x * wey[4];
    z0 += q1.y * wex[5];  z1 += q1.y * wey[5];
    z0 += q1.z * wex[6];  z1 += q1.z * wey[6];
    z0 += q1.w * wex[7];  z1 += q1.w * wey[7];
    z0 += q2.x * wex[8];  z1 += q2.x * wey[8];
    z0 += q2.y * wex[9];  z1 += q2.y * wey[9];
    z0 += q2.z * wex[10]; z1 += q2.z * wey[10];
    z0 += q2.w * wex[11]; z1 += q2.w * wey[11];
    z0 += q3.x * wex[12]; z1 += q3.x * wey[12];
    z0 += q3.y * wex[13]; z1 += q3.y * wey[13];
    z0 += q3.z * wex[14]; z1 += q3.z * wey[14];
    z0 += q3.w * wex[15]; z1 += q3.w * wey[15];
    acc0 += fmaxf(bf2f((ushort)(yu & 0xFFFF)) + z0, 0.f);
    acc1 += fmaxf(bf2f((ushort)(yu >> 16)) + z1, 0.f);
  };

  int j = beg;
  for (; j + 4 <= end; j += 4) {
    int2 p0 = sev[j], p1 = sev[j + 1], p2 = sev[j + 2], p3 = sev[j + 3];
    uint o0 = (uint)__builtin_amdgcn_readfirstlane(p0.x) * 64u + (uint)lane;
    uint o1 = (uint)__builtin_amdgcn_readfirstlane(p1.x) * 64u + (uint)lane;
    uint o2 = (uint)__builtin_amdgcn_readfirstlane(p2.x) * 64u + (uint)lane;
    uint o3 = (uint)__builtin_amdgcn_readfirstlane(p3.x) * 64u + (uint)lane;
    int  e0 = __builtin_amdgcn_readfirstlane(p0.y);
    int  e1 = __builtin_amdgcn_readfirstlane(p1.y);
    int  e2 = __builtin_amdgcn_readfirstlane(p2.y);
    int  e3 = __builtin_amdgcn_readfirstlane(p3.y);
    uint y0 = ybf[o0];
    uint y1 = ybf[o1];
    uint y2 = ybf[o2];
    uint y3 = ybf[o3];
    float4 a00 = ld4t<FAST>(ea, ef, (size_t)e0 * 4 + 0);
    float4 a01 = ld4t<FAST>(ea, ef, (size_t)e0 * 4 + 1);
    float4 a02 = ld4t<FAST>(ea, ef, (size_t)e0 * 4 + 2);
    float4 a03 = ld4t<FAST>(ea, ef, (size_t)e0 * 4 + 3);
    float4 a10 = ld4t<FAST>(ea, ef, (size_t)e1 * 4 + 0);
    float4 a11 = ld4t<FAST>(ea, ef, (size_t)e1 * 4 + 1);
    float4 a12 = ld4t<FAST>(ea, ef, (size_t)e1 * 4 + 2);
    float4 a13 = ld4t<FAST>(ea, ef, (size_t)e1 * 4 + 3);
    float4 a20 = ld4t<FAST>(ea, ef, (size_t)e2 * 4 + 0);
    float4 a21 = ld4t<FAST>(ea, ef, (size_t)e2 * 4 + 1);
    float4 a22 = ld4t<FAST>(ea, ef, (size_t)e2 * 4 + 2);
    float4 a23 = ld4t<FAST>(ea, ef, (size_t)e2 * 4 + 3);
    float4 a30 = ld4t<FAST>(ea, ef, (size_t)e3 * 4 + 0);
    float4 a31 = ld4t<FAST>(ea, ef, (size_t)e3 * 4 + 1);
    float4 a32 = ld4t<FAST>(ea, ef, (size_t)e3 * 4 + 2);
    float4 a33 = ld4t<FAST>(ea, ef, (size_t)e3 * 4 + 3);
    edge(y0, a00, a01, a02, a03);
    edge(y1, a10, a11, a12, a13);
    edge(y2, a20, a21, a22, a23);
    edge(y3, a30, a31, a32, a33);
  }
  for (; j < end; ++j) {  // tail (scalar trip count)
    int2 p = sev[j];
    uint o = (uint)__builtin_amdgcn_readfirstlane(p.x) * 64u + (uint)lane;
    int  e = __builtin_amdgcn_readfirstlane(p.y);
    uint yu = ybf[o];
    float4 q0 = ld4t<FAST>(ea, ef, (size_t)e * 4 + 0);
    float4 q1 = ld4t<FAST>(ea, ef, (size_t)e * 4 + 1);
    float4 q2 = ld4t<FAST>(ea, ef, (size_t)e * 4 + 2);
    float4 q3 = ld4t<FAST>(ea, ef, (size_t)e * 4 + 3);
    edge(yu, q0, q1, q2, q3);
  }
  agg[(size_t)n * CH + 2 * lane]     = acc0;
  agg[(size_t)n * CH + 2 * lane + 1] = acc1;
}

__global__ __launch_bounds__(256, 4) void agg_csr(const uint* __restrict__ ybf,
                                                  const void* __restrict__ ea,
                                                  const void* __restrict__ W,
                                                  const int* __restrict__ rowptr,
                                                  const int2* __restrict__ sev,
                                                  const int* __restrict__ flags,
                                                  float* __restrict__ agg) {
  const int wave = threadIdx.x >> 6;
  const int lane = threadIdx.x & 63;
  const int ef = flags[2], wf = flags[3];
  if (ef & wf) agg_body<1>(ybf, ea, W, rowptr, sev, ef, wf, agg, wave, lane);
  else         agg_body<0>(ybf, ea, W, rowptr, sev, ef, wf, agg, wave, lane);
}

// ---------------------------------------------------------------- update + L2-normalize + bias fused:
// GEMM then in-wave row norm (6-step shfl). Writes layer output directly.
// Layer 2 reads its own rows of h (=d_out) -- staged in LDS before any store,
// blocks own disjoint rows.
template <int FAST>
__device__ __forceinline__ void upd_body(const void* __restrict__ x, int xf,
                                         const float* __restrict__ agg,
                                         const int* __restrict__ rowptr,
                                         const void* __restrict__ W, int wf,
                                         const void* __restrict__ bupd,
                                         const void* __restrict__ bias,
                                         float* __restrict__ out, int relu,
                                         int wave, int lane, float (*xs)[KUPD]) {
  const int n0 = (blockIdx.x * 4 + wave) * NPW;
#pragma unroll
  for (int r = 0; r < NPW; ++r) {
    int n = n0 + r;
    float2 a = ld2t<FAST>(x, xf, (size_t)n * 64 + lane);
    xs[r][2 * lane]     = a.x;
    xs[r][2 * lane + 1] = a.y;
    int c = rowptr[n + 1] - rowptr[n];
    float inv = 1.f / (float)(c > 1 ? c : 1);
    xs[r][CH + 2 * lane]     = agg[(size_t)n * CH + 2 * lane] * inv;
    xs[r][CH + 2 * lane + 1] = agg[(size_t)n * CH + 2 * lane + 1] * inv;
  }
  __syncthreads();

  float acc0[NPW], acc1[NPW];
#pragma unroll
  for (int r = 0; r < NPW; ++r) { acc0[r] = 0.f; acc1[r] = 0.f; }

#pragma unroll 4
  for (int k = 0; k < KUPD; k += 2) {
    float2 w0 = ld2t<FAST>(W, wf, (size_t)k * 64 + lane);
    float2 w1 = ld2t<FAST>(W, wf, (size_t)(k + 1) * 64 + lane);
#pragma unroll
    for (int r = 0; r < NPW; ++r) {
      float2 a = *(const float2*)&xs[r][k];
      acc0[r] += a.x * w0.x;
      acc1[r] += a.x * w0.y;
      acc0[r] += a.y * w1.x;
      acc1[r] += a.y * w1.y;
    }
  }

  float2 b  = ld2t<FAST>(bupd, wf, lane);
  float2 bi = ld2t<FAST>(bias, wf, lane);
#pragma unroll
  for (int r = 0; r < NPW; ++r) {
    float r0 = acc0[r] + b.x;
    float r1 = acc1[r] + b.y;
    float ss = r0 * r0 + r1 * r1;
#pragma unroll
    for (int o = 32; o; o >>= 1) ss += __shfl_xor(ss, o);
    float innv = 1.0f / fmaxf(sqrtf(ss), 1e-12f);
    float o0 = r0 * innv + bi.x;
    float o1 = r1 * innv + bi.y;
    if (relu) {
      o0 = fmaxf(o0, 0.0f);
      o1 = fmaxf(o1, 0.0f);
    }
    size_t n = (size_t)(n0 + r);
    out[n * CH + 2 * lane]     = o0;
    out[n * CH + 2 * lane + 1] = o1;
  }
}

__global__ __launch_bounds__(256) void upd_fused(const void* __restrict__ x, int x_sel,
                                                 const float* __restrict__ agg,
                                                 const int* __restrict__ rowptr,
                                                 const void* __restrict__ W,
                                                 const void* __restrict__ bupd,
                                                 const void* __restrict__ bias,
                                                 const int* __restrict__ flags,
                                                 float* __restrict__ out,
                                                 int relu) {
  __shared__ float xs[4][NPW][KUPD];  // 32 KB
  const int wave = threadIdx.x >> 6;
  const int lane = threadIdx.x & 63;
  const int xf = resolve_f32(x_sel, flags), wf = flags[3];
  if (xf & wf) upd_body<1>(x, xf, agg, rowptr, W, wf, bupd, bias, out, relu, wave, lane, xs[wave]);
  else         upd_body<0>(x, xf, agg, rowptr, W, wf, bupd, bias, out, relu, wave, lane, xs[wave]);
}

// ---------------------------------------------------------------- host
extern "C" void kernel_launch(void* const* d_in, const int* in_sizes, int n_in,
                              void* d_out, int out_size, void* d_ws, size_t ws_size,
                              hipStream_t stream) {
  const void* x   = d_in[0];
  const int*  ei  = (const int*)d_in[1];
  const void* ea  = d_in[2];
  const void* wm1 = d_in[3];
  const void* bm1 = d_in[4];
  const void* wu1 = d_in[5];
  const void* bu1 = d_in[6];
  const void* bi1 = d_in[7];
  const void* wm2 = d_in[8];
  const void* bm2 = d_in[9];
  const void* wu2 = d_in[10];
  const void* bu2 = d_in[11];
  const void* bi2 = d_in[12];
  float* out = (float*)d_out;

  // Workspace (~92 MB): flags | cnt | fill | rowptr | sev (CSR {src,eid}) | agg | ybf (bf16).
  char* base = (char*)d_ws;
  size_t off = 0;
  auto alloc = [&](size_t b) { size_t o = off; off += (b + 255) & ~(size_t)255; return o; };
  size_t flags_o = alloc(16);
  size_t cnt_o   = alloc((size_t)N_NODES * 4);
  size_t fill_o  = alloc((size_t)N_NODES * 4);
  size_t zero_end = off;                       // memset covers flags|cnt|fill only
  size_t rowp_o  = alloc((size_t)(N_NODES + 1) * 4);
  size_t sev_o   = alloc((size_t)N_EDGES * 8);
  size_t agg_o   = alloc((size_t)N_NODES * CH * 4);
  size_t y_o     = alloc((size_t)N_NODES * CH * 2);   // packed bf16
  (void)ws_size; (void)n_in; (void)in_sizes; (void)out_size;

  int*    flags = (int*)(base + flags_o);
  int*    cntp  = (int*)(base + cnt_o);
  int*    fillp = (int*)(base + fill_o);
  int*    rowp  = (int*)(base + rowp_o);
  int2*   sevp  = (int2*)(base + sev_o);
  float*  aggp  = (float*)(base + agg_o);
  uint*   ybfp  = (uint*)(base + y_o);
  float*  hp    = out;                  // layer-1 output (f32) lives in d_out

  hipMemsetAsync(base, 0, zero_end, stream);
  detect_kernel<<<1, 256, 0, stream>>>(ei, (const ushort*)x, (const ushort*)ea,
                                       (const ushort*)wm1, flags);
  count_kernel<<<(N_EDGES + 255) / 256, 256, 0, stream>>>(ei, flags, cntp);
  scan_kernel<<<1, 1024, 0, stream>>>(cntp, rowp);
  scatter_kernel<<<(N_EDGES + 255) / 256, 256, 0, stream>>>(ei, flags, rowp, fillp, sevp);

  const int ggrid = N_NODES / (4 * NPW);  // 3125
  const int agrid = N_NODES / 4;          // 25000 (one wave per node)

  // ---- layer 1
  gemm_node<<<ggrid, 256, 0, stream>>>(x, 1, wm1, bm1, flags, ybfp);
  agg_csr<<<agrid, 256, 0, stream>>>(ybfp, ea, wm1, rowp, sevp, flags, aggp);
  upd_fused<<<ggrid, 256, 0, stream>>>(x, 1, aggp, rowp, wu1, bu1, bi1, flags, hp, 1);

  // ---- layer 2 (h is f32 in d_out -> x_sel=2 forces f32)
  gemm_node<<<ggrid, 256, 0, stream>>>(hp, 2, wm2, bm2, flags, ybfp);
  agg_csr<<<agrid, 256, 0, stream>>>(ybfp, ea, wm2, rowp, sevp, flags, aggp);
  upd_fused<<<ggrid, 256, 0, stream>>>(hp, 2, aggp, rowp, wu2, bu2, bi2, flags, out, 0);
}

// Round 6
// 1242.013 us; speedup vs baseline: 1.1356x; 1.1356x over previous
//
#include <hip/hip_runtime.h>
#include <stdint.h>

#define N_NODES 100000
#define N_EDGES 1600000
#define CH 128
#define EDGE_DIM 16
#define KUPD 256
#define NPW 8

typedef __attribute__((ext_vector_type(8))) short short8v;   // 8 bf16 (4 VGPRs)
typedef __attribute__((ext_vector_type(4))) float f32x4;

__device__ __forceinline__ float bf2f(ushort u) {
  union { uint i; float f; } c; c.i = ((uint)u) << 16; return c.f;
}
__device__ __forceinline__ ushort f2bf(float f) {
  union { float f; uint i; } c; c.f = f;
  return (ushort)((c.i + 0x7FFFu + ((c.i >> 16) & 1u)) >> 16);
}
__device__ __forceinline__ float ldf(const void* p, int f32, size_t i) {
  return f32 ? ((const float*)p)[i] : bf2f(((const ushort*)p)[i]);
}
__device__ __forceinline__ float2 ld2(const void* p, int f32, size_t pi) {
  if (f32) return ((const float2*)p)[pi];
  uint u = ((const uint*)p)[pi];
  return make_float2(bf2f((ushort)(u & 0xFFFF)), bf2f((ushort)(u >> 16)));
}
__device__ __forceinline__ float4 ld4(const void* p, int f32, size_t qi) {
  if (f32) return ((const float4*)p)[qi];
  uint2 u = ((const uint2*)p)[qi];
  float4 r;
  r.x = bf2f((ushort)(u.x & 0xFFFF)); r.y = bf2f((ushort)(u.x >> 16));
  r.z = bf2f((ushort)(u.y & 0xFFFF)); r.w = bf2f((ushort)(u.y >> 16));
  return r;
}
template <int FAST>
__device__ __forceinline__ float2 ld2t(const void* p, int f32, size_t pi) {
  if (FAST) return ((const float2*)p)[pi];
  return ld2(p, f32, pi);
}
// x_sel: 0 = force bf16, 1 = use detected x flag, 2 = force f32
__device__ __forceinline__ int resolve_f32(int x_sel, const int* flags) {
  return (x_sel == 2) ? 1 : (x_sel == 1 ? flags[1] : 0);
}
// MFMA A/B k-mapping candidates. g = lane>>4, j = frag element 0..7.
// MAP0 (interleaved, matches m156/m162 tr_b16-derived layout), MAP1 (contiguous).
__device__ __forceinline__ int kmap(int MAP, int g, int j, int step) {
  return MAP ? (step * 32 + 8 * g + j)
             : (step * 32 + 16 * (j >> 2) + 4 * g + (j & 3));
}

// ---------------------------------------------------------------- runtime layout/dtype detection
// flags[0]=1 -> edge_index int32 [2,E]. flags[1..3]=1 -> x / edge_attr / weights are f32.
// flags[4] = MFMA k-mapping (0/1) or 2 = no candidate verified -> f32 fallback.
__global__ __launch_bounds__(256) void detect_kernel(const int* __restrict__ ei,
                                                     const ushort* __restrict__ xu,
                                                     const ushort* __restrict__ eau,
                                                     const ushort* __restrict__ wu,
                                                     int* __restrict__ flags) {
  int any = 0, fx = 0, fe = 0, fw = 0;
  for (int i = threadIdx.x; i < 4096; i += 256) any |= ei[2 * i + 1];
  for (int i = threadIdx.x; i < 16384; i += 256) {
    fx |= (((xu[2 * i] >> 7) & 0xFF) == 0xFF);
    fe |= (((eau[2 * i] >> 7) & 0xFF) == 0xFF);
  }
  for (int i = threadIdx.x; i < 8192; i += 256) {
    fw |= (((wu[2 * i] >> 7) & 0xFF) == 0xFF);
  }
  if (any) atomicOr(flags + 0, 1);
  if (fx)  atomicOr(flags + 1, 1);
  if (fe)  atomicOr(flags + 2, 1);
  if (fw)  atomicOr(flags + 3, 1);
}

// ---------------------------------------------------------------- MFMA layout self-verification
// One wave. Known asymmetric small-integer (bf16-exact) A[16x32], B[32x16]:
// scalar reference vs MFMA under each candidate k-mapping, exact compare at the
// m89-verified C positions (col=lane&15, row=(lane>>4)*4+reg). Winner -> flags[4].
__global__ __launch_bounds__(64) void mfma_probe(int* __restrict__ flags) {
  __shared__ ushort A[16 * 32];
  __shared__ ushort B[32 * 16];
  const int lane = threadIdx.x;
  for (int idx = lane; idx < 512; idx += 64) {
    int i = idx >> 5, k = idx & 31;
    A[idx] = f2bf((float)((i * 5 + k * 3) % 13 - 6));
    int k2 = idx >> 4, c = idx & 15;
    B[idx] = f2bf((float)((k2 * 7 + c * 11) % 15 - 7));
  }
  __syncthreads();
  const int col = lane & 15, g = lane >> 4;
  float cr[4];
#pragma unroll
  for (int r = 0; r < 4; ++r) {
    int row = g * 4 + r;
    float s = 0.f;
    for (int k = 0; k < 32; ++k) s += bf2f(A[row * 32 + k]) * bf2f(B[k * 16 + col]);
    cr[r] = s;
  }
  int win = 2;
  for (int MAP = 0; MAP < 2; ++MAP) {
    if (win != 2) break;
    short8v a, b;
#pragma unroll
    for (int j = 0; j < 8; ++j) {
      int k = kmap(MAP, g, j, 0);
      a[j] = (short)A[(lane & 15) * 32 + k];
      b[j] = (short)B[k * 16 + col];
    }
    f32x4 z = {0.f, 0.f, 0.f, 0.f};
    f32x4 d = __builtin_amdgcn_mfma_f32_16x16x32_bf16(a, b, z, 0, 0, 0);
    int good = 1;
#pragma unroll
    for (int r = 0; r < 4; ++r) good &= (d[r] == cr[r]);
    if (__all(good)) win = MAP;
  }
  if (lane == 0) flags[4] = win;
}

__device__ __forceinline__ void load_edge(const int* __restrict__ ei, int i32, int e,
                                          int& s, int& d) {
  if (i32) { s = ei[e]; d = ei[N_EDGES + e]; }
  else     { s = ei[2 * e]; d = ei[2 * N_EDGES + 2 * e]; }
  s = min(max(s, 0), N_NODES - 1);
  d = min(max(d, 0), N_NODES - 1);
}

// ---------------------------------------------------------------- degree count (dst only)
__global__ __launch_bounds__(256) void count_kernel(const int* __restrict__ ei,
                                                    const int* __restrict__ flags,
                                                    int* __restrict__ cnt) {
  int e = blockIdx.x * 256 + threadIdx.x;
  if (e >= N_EDGES) return;
  int d = flags[0] ? ei[N_EDGES + e] : ei[2 * N_EDGES + 2 * e];
  d = min(max(d, 0), N_NODES - 1);
  atomicAdd(&cnt[d], 1);
}

// ---------------------------------------------------------------- exclusive prefix scan of cnt -> rowptr
__global__ __launch_bounds__(1024) void scan_kernel(const int* __restrict__ cnt,
                                                    int* __restrict__ rowptr) {
  __shared__ int part[1024];
  const int t = threadIdx.x;
  const int CHUNK = (N_NODES + 1023) / 1024;  // 98
  int base = t * CHUNK;
  int lim = min(base + CHUNK, N_NODES);
  int s = 0;
  for (int i = base; i < lim; ++i) s += cnt[i];
  part[t] = s;
  __syncthreads();
  for (int off = 1; off < 1024; off <<= 1) {
    int v = (t >= off) ? part[t - off] : 0;
    __syncthreads();
    part[t] += v;
    __syncthreads();
  }
  int excl = (t == 0) ? 0 : part[t - 1];
  for (int i = base; i < lim; ++i) { rowptr[i] = excl; excl += cnt[i]; }
  if (t == 1023) rowptr[N_NODES] = part[1023];
}

// ---------------------------------------------------------------- CSR scatter: {src, eid} sorted by dst
__global__ __launch_bounds__(256) void scatter_kernel(const int* __restrict__ ei,
                                                      const int* __restrict__ flags,
                                                      const int* __restrict__ rowptr,
                                                      int* __restrict__ fill,
                                                      int2* __restrict__ sev) {
  int e = blockIdx.x * 256 + threadIdx.x;
  if (e >= N_EDGES) return;
  int s, d;
  load_edge(ei, flags[0], e, s, d);
  int pos = atomicAdd(&fill[d], 1);
  sev[rowptr[d] + pos] = make_int2(s, e);
}

// ---------------------------------------------------------------- W pre-shuffle into frag order
// wsh[(t*8+step)*512 + lane*8 + j] = bf16(W[kmap(lane>>4, j, step)][t*16 + (lane&15)])
// so each lane's B-frag is ONE coalesced 16B load in the hot GEMM.
__global__ __launch_bounds__(256) void wshuf_build(const void* __restrict__ W,
                                                   const int* __restrict__ flags,
                                                   ushort* __restrict__ wsh) {
  const int MAP = flags[4], wf = flags[3];
  if (MAP == 2) return;
  int tid = blockIdx.x * 256 + threadIdx.x;  // 4096 = 8 tiles * 8 steps * 64 lanes
  if (tid >= 4096) return;
  int lane = tid & 63, ts = tid >> 6;
  int t = ts >> 3, step = ts & 7;
  int col = t * 16 + (lane & 15), g = lane >> 4;
#pragma unroll
  for (int j = 0; j < 8; ++j) {
    int k = kmap(MAP, g, j, step);
    wsh[(size_t)ts * 512 + lane * 8 + j] = f2bf(ldf(W, wf, (size_t)k * CH + col));
  }
}

// ---------------------------------------------------------------- node-level GEMM: y = x @ W[0:128] + b -> packed bf16
template <int FAST>
__device__ __forceinline__ void gemm_body(const void* __restrict__ x, int xf,
                                          const void* __restrict__ W, int wf,
                                          const void* __restrict__ b,
                                          uint* __restrict__ ybf,
                                          int wave, int lane, float (*xs)[CH]) {
  const int n0 = (blockIdx.x * 4 + wave) * NPW;  // N = 32*gridDim exactly
#pragma unroll
  for (int r = 0; r < NPW; ++r) {
    float2 a = ld2t<FAST>(x, xf, (size_t)(n0 + r) * 64 + lane);
    xs[r][2 * lane]     = a.x;
    xs[r][2 * lane + 1] = a.y;
  }
  __syncthreads();

  float acc0[NPW], acc1[NPW];
#pragma unroll
  for (int r = 0; r < NPW; ++r) { acc0[r] = 0.f; acc1[r] = 0.f; }

#pragma unroll 4
  for (int k = 0; k < CH; k += 2) {
    float2 w0 = ld2t<FAST>(W, wf, (size_t)k * 64 + lane);
    float2 w1 = ld2t<FAST>(W, wf, (size_t)(k + 1) * 64 + lane);
#pragma unroll
    for (int r = 0; r < NPW; ++r) {
      float2 a = *(const float2*)&xs[r][k];
      acc0[r] += a.x * w0.x;
      acc1[r] += a.x * w0.y;
      acc0[r] += a.y * w1.x;
      acc1[r] += a.y * w1.y;
    }
  }

  float2 bb = ld2t<FAST>(b, wf, lane);
#pragma unroll
  for (int r = 0; r < NPW; ++r) {
    uint pk = (uint)f2bf(acc0[r] + bb.x) | ((uint)f2bf(acc1[r] + bb.y) << 16);
    ybf[(uint)(n0 + r) * 64u + (uint)lane] = pk;
  }
}

__global__ __launch_bounds__(256) void gemm_node(const void* __restrict__ x, int x_sel,
                                                 const void* __restrict__ W,
                                                 const void* __restrict__ b,
                                                 const int* __restrict__ flags,
                                                 uint* __restrict__ ybf) {
  __shared__ float xs[4][NPW][CH];  // 16 KB
  const int wave = threadIdx.x >> 6;
  const int lane = threadIdx.x & 63;
  const int xf = resolve_f32(x_sel, flags), wf = flags[3];
  if (xf & wf) gemm_body<1>(x, xf, W, wf, b, ybf, wave, lane, xs[wave]);
  else         gemm_body<0>(x, xf, W, wf, b, ybf, wave, lane, xs[wave]);
}

// ---------------------------------------------------------------- CSR aggregation (R4 form, reverted):
// One wave per dst node, 4-edge batches, vector loads. R5's scalar-loop variant
// cost occupancy (48->38%) for no gain -- reverted to the measured-best body.
__global__ __launch_bounds__(256, 4) void agg_csr(const uint* __restrict__ ybf,
                                                  const void* __restrict__ ea,
                                                  const void* __restrict__ W,
                                                  const int* __restrict__ rowptr,
                                                  const int2* __restrict__ sev,
                                                  const int* __restrict__ flags,
                                                  float* __restrict__ agg) {
  const int wave = threadIdx.x >> 6;
  const int lane = threadIdx.x & 63;
  const int ef = flags[2], wf = flags[3];

  float wex[EDGE_DIM], wey[EDGE_DIM];
#pragma unroll
  for (int k = 0; k < EDGE_DIM; ++k) {
    float2 wv = ld2(W, wf, (size_t)(CH + k) * 64 + lane);
    wex[k] = wv.x; wey[k] = wv.y;
  }

  const int n = blockIdx.x * 4 + wave;  // grid = N/4 exactly
  const int beg = rowptr[n], end = rowptr[n + 1];
  float acc0 = 0.f, acc1 = 0.f;

  auto edge = [&](uint yu, float4 q0, float4 q1, float4 q2, float4 q3) {
    float av[16] = {q0.x, q0.y, q0.z, q0.w, q1.x, q1.y, q1.z, q1.w,
                    q2.x, q2.y, q2.z, q2.w, q3.x, q3.y, q3.z, q3.w};
    float z0 = 0.f, z1 = 0.f;
#pragma unroll
    for (int k = 0; k < EDGE_DIM; ++k) {
      z0 += av[k] * wex[k];
      z1 += av[k] * wey[k];
    }
    acc0 += fmaxf(bf2f((ushort)(yu & 0xFFFF)) + z0, 0.f);
    acc1 += fmaxf(bf2f((ushort)(yu >> 16)) + z1, 0.f);
  };

  int j = beg;
  for (; j + 4 <= end; j += 4) {
    int2 p0 = sev[j], p1 = sev[j + 1], p2 = sev[j + 2], p3 = sev[j + 3];
    int s0 = __builtin_amdgcn_readfirstlane(p0.x), e0 = __builtin_amdgcn_readfirstlane(p0.y);
    int s1 = __builtin_amdgcn_readfirstlane(p1.x), e1 = __builtin_amdgcn_readfirstlane(p1.y);
    int s2 = __builtin_amdgcn_readfirstlane(p2.x), e2 = __builtin_amdgcn_readfirstlane(p2.y);
    int s3 = __builtin_amdgcn_readfirstlane(p3.x), e3 = __builtin_amdgcn_readfirstlane(p3.y);
    uint y0 = ybf[(size_t)s0 * 64 + lane];
    uint y1 = ybf[(size_t)s1 * 64 + lane];
    uint y2 = ybf[(size_t)s2 * 64 + lane];
    uint y3 = ybf[(size_t)s3 * 64 + lane];
    float4 a00 = ld4(ea, ef, (size_t)e0 * 4 + 0);
    float4 a01 = ld4(ea, ef, (size_t)e0 * 4 + 1);
    float4 a02 = ld4(ea, ef, (size_t)e0 * 4 + 2);
    float4 a03 = ld4(ea, ef, (size_t)e0 * 4 + 3);
    float4 a10 = ld4(ea, ef, (size_t)e1 * 4 + 0);
    float4 a11 = ld4(ea, ef, (size_t)e1 * 4 + 1);
    float4 a12 = ld4(ea, ef, (size_t)e1 * 4 + 2);
    float4 a13 = ld4(ea, ef, (size_t)e1 * 4 + 3);
    float4 a20 = ld4(ea, ef, (size_t)e2 * 4 + 0);
    float4 a21 = ld4(ea, ef, (size_t)e2 * 4 + 1);
    float4 a22 = ld4(ea, ef, (size_t)e2 * 4 + 2);
    float4 a23 = ld4(ea, ef, (size_t)e2 * 4 + 3);
    float4 a30 = ld4(ea, ef, (size_t)e3 * 4 + 0);
    float4 a31 = ld4(ea, ef, (size_t)e3 * 4 + 1);
    float4 a32 = ld4(ea, ef, (size_t)e3 * 4 + 2);
    float4 a33 = ld4(ea, ef, (size_t)e3 * 4 + 3);
    edge(y0, a00, a01, a02, a03);
    edge(y1, a10, a11, a12, a13);
    edge(y2, a20, a21, a22, a23);
    edge(y3, a30, a31, a32, a33);
  }
  for (; j < end; ++j) {
    int2 p = sev[j];
    int s = __builtin_amdgcn_readfirstlane(p.x), e = __builtin_amdgcn_readfirstlane(p.y);
    uint yu = ybf[(size_t)s * 64 + lane];
    float4 q0 = ld4(ea, ef, (size_t)e * 4 + 0);
    float4 q1 = ld4(ea, ef, (size_t)e * 4 + 1);
    float4 q2 = ld4(ea, ef, (size_t)e * 4 + 2);
    float4 q3 = ld4(ea, ef, (size_t)e * 4 + 3);
    edge(yu, q0, q1, q2, q3);
  }
  agg[(size_t)n * CH + 2 * lane]     = acc0;
  agg[(size_t)n * CH + 2 * lane + 1] = acc1;
}

// ---------------------------------------------------------------- update GEMM on matrix cores + fused norm
// One wave = 16 rows x 128 cols, K=256: 8 col-tiles x 8 K-steps = 64 MFMAs.
// A = [x || agg/cnt] staged bf16 in a per-wave 8KB LDS slice ([16][256], XOR
// bank-swizzle byte^((row&7)<<4)); B-frags from the pre-shuffled wsh buffer
// (one 16B coalesced load each). Epilogue: row-norm via 16-lane shfl groups
// (C layout col=lane&15, row=(lane>>4)*4+reg). Waves fully independent -> no
// barriers (per-wave LDS; explicit lgkmcnt fence between stage and frag reads).
template <int MAP>
__device__ __forceinline__ void upd_mfma_body(const void* __restrict__ x, int xf,
                                              const float* __restrict__ agg,
                                              const int* __restrict__ rowptr,
                                              const ushort* __restrict__ wsh,
                                              const void* __restrict__ bupd, int wf,
                                              const void* __restrict__ bias,
                                              float* __restrict__ out, int relu,
                                              int n0, int lane, char* lds) {
  const int srow = lane >> 2;   // staged row 0..15 (4 lanes each)
  const int q = lane & 3;
  {
    int c = rowptr[n0 + srow + 1] - rowptr[n0 + srow];
    float inv = 1.f / (float)(c > 1 ? c : 1);
    uint sw = (uint)((srow & 7) << 4);
#pragma unroll
    for (int i = 0; i < 8; ++i) {
      int qi = q + 4 * i;  // float4 index within the 128-wide half-row
      float4 v = ld4(x, xf, (size_t)(n0 + srow) * 32 + qi);
      uint2 pk;
      pk.x = (uint)f2bf(v.x) | ((uint)f2bf(v.y) << 16);
      pk.y = (uint)f2bf(v.z) | ((uint)f2bf(v.w) << 16);
      *(uint2*)(lds + (((uint)srow * 512u + (uint)qi * 8u) ^ sw)) = pk;
      float4 w = ((const float4*)agg)[(size_t)(n0 + srow) * 32 + qi];
      uint2 pk2;
      pk2.x = (uint)f2bf(w.x * inv) | ((uint)f2bf(w.y * inv) << 16);
      pk2.y = (uint)f2bf(w.z * inv) | ((uint)f2bf(w.w * inv) << 16);
      *(uint2*)(lds + (((uint)srow * 512u + 256u + (uint)qi * 8u) ^ sw)) = pk2;
    }
  }
  asm volatile("s_waitcnt lgkmcnt(0)" ::: "memory");
  __builtin_amdgcn_sched_barrier(0);

  const int col = lane & 15, g = lane >> 4;
  const int ra = lane & 15;               // A-frag row
  const uint asw = (uint)((ra & 7) << 4);
  f32x4 acc[8];
#pragma unroll
  for (int t = 0; t < 8; ++t) acc[t] = (f32x4){0.f, 0.f, 0.f, 0.f};

#pragma unroll
  for (int step = 0; step < 8; ++step) {
    short8v a;
    if (MAP) {  // contiguous: one 16B read
      uint byte = (uint)ra * 512u + (uint)(step * 32 + 8 * g) * 2u;
      *(uint4*)&a = *(const uint4*)(lds + (byte ^ asw));
    } else {    // interleaved: two 8B reads (k 4g..4g+3, 16+4g..16+4g+3)
      uint b0 = (uint)ra * 512u + (uint)(step * 32 + 4 * g) * 2u;
      uint b1 = b0 + 32u;
      uint2 lo = *(const uint2*)(lds + (b0 ^ asw));
      uint2 hi = *(const uint2*)(lds + (b1 ^ asw));
      uint4 pk = make_uint4(lo.x, lo.y, hi.x, hi.y);
      *(uint4*)&a = pk;
    }
#pragma unroll
    for (int t = 0; t < 8; ++t) {
      short8v b = *(const short8v*)(wsh + ((size_t)(t * 8 + step) * 512 + lane * 8));
      acc[t] = __builtin_amdgcn_mfma_f32_16x16x32_bf16(a, b, acc[t], 0, 0, 0);
    }
  }

  float bu[8], bi[8];
#pragma unroll
  for (int t = 0; t < 8; ++t) {
    bu[t] = ldf(bupd, wf, t * 16 + col);
    bi[t] = ldf(bias, wf, t * 16 + col);
  }
  float raw[8][4];
  float ss[4] = {0.f, 0.f, 0.f, 0.f};
#pragma unroll
  for (int t = 0; t < 8; ++t)
#pragma unroll
    for (int r = 0; r < 4; ++r) {
      float v = acc[t][r] + bu[t];
      raw[t][r] = v;
      ss[r] += v * v;
    }
#pragma unroll
  for (int r = 0; r < 4; ++r)
#pragma unroll
    for (int o = 1; o < 16; o <<= 1) ss[r] += __shfl_xor(ss[r], o);
#pragma unroll
  for (int r = 0; r < 4; ++r) {
    float inv = 1.0f / fmaxf(sqrtf(ss[r]), 1e-12f);
    int row = g * 4 + r;
#pragma unroll
    for (int t = 0; t < 8; ++t) {
      float o = raw[t][r] * inv + bi[t];
      if (relu) o = fmaxf(o, 0.f);
      out[(size_t)(n0 + row) * CH + t * 16 + col] = o;
    }
  }
}

// f32 fallback (flags[4]==2): two 8-row chunks per wave, per-wave LDS, no barriers.
__device__ __forceinline__ void upd_f32_body(const void* __restrict__ x, int xf,
                                             const float* __restrict__ agg,
                                             const int* __restrict__ rowptr,
                                             const void* __restrict__ W, int wf,
                                             const void* __restrict__ bupd,
                                             const void* __restrict__ bias,
                                             float* __restrict__ out, int relu,
                                             int wave_n0, int lane, char* ldsc) {
  float* xs = (float*)ldsc;  // [8][256] f32 = 8 KB per-wave slice
  for (int c = 0; c < 2; ++c) {
    int n0 = wave_n0 + c * 8;
#pragma unroll
    for (int r = 0; r < NPW; ++r) {
      int n = n0 + r;
      float2 a = ld2(x, xf, (size_t)n * 64 + lane);
      xs[r * 256 + 2 * lane]     = a.x;
      xs[r * 256 + 2 * lane + 1] = a.y;
      int cd = rowptr[n + 1] - rowptr[n];
      float inv = 1.f / (float)(cd > 1 ? cd : 1);
      xs[r * 256 + CH + 2 * lane]     = agg[(size_t)n * CH + 2 * lane] * inv;
      xs[r * 256 + CH + 2 * lane + 1] = agg[(size_t)n * CH + 2 * lane + 1] * inv;
    }
    asm volatile("s_waitcnt lgkmcnt(0)" ::: "memory");
    __builtin_amdgcn_sched_barrier(0);

    float acc0[NPW], acc1[NPW];
#pragma unroll
    for (int r = 0; r < NPW; ++r) { acc0[r] = 0.f; acc1[r] = 0.f; }
#pragma unroll 4
    for (int k = 0; k < KUPD; k += 2) {
      float2 w0 = ld2(W, wf, (size_t)k * 64 + lane);
      float2 w1 = ld2(W, wf, (size_t)(k + 1) * 64 + lane);
#pragma unroll
      for (int r = 0; r < NPW; ++r) {
        float2 a = *(const float2*)&xs[r * 256 + k];
        acc0[r] += a.x * w0.x;
        acc1[r] += a.x * w0.y;
        acc0[r] += a.y * w1.x;
        acc1[r] += a.y * w1.y;
      }
    }
    float2 b  = ld2(bupd, wf, lane);
    float2 bi = ld2(bias, wf, lane);
#pragma unroll
    for (int r = 0; r < NPW; ++r) {
      float r0 = acc0[r] + b.x;
      float r1 = acc1[r] + b.y;
      float sq = r0 * r0 + r1 * r1;
#pragma unroll
      for (int o = 32; o; o >>= 1) sq += __shfl_xor(sq, o);
      float innv = 1.0f / fmaxf(sqrtf(sq), 1e-12f);
      float o0 = r0 * innv + bi.x;
      float o1 = r1 * innv + bi.y;
      if (relu) { o0 = fmaxf(o0, 0.f); o1 = fmaxf(o1, 0.f); }
      size_t n = (size_t)(n0 + r);
      out[n * CH + 2 * lane]     = o0;
      out[n * CH + 2 * lane + 1] = o1;
    }
  }
}

__global__ __launch_bounds__(256) void upd_fused(const void* __restrict__ x, int x_sel,
                                                 const float* __restrict__ agg,
                                                 const int* __restrict__ rowptr,
                                                 const ushort* __restrict__ wsh,
                                                 const void* __restrict__ W,
                                                 const void* __restrict__ bupd,
                                                 const void* __restrict__ bias,
                                                 const int* __restrict__ flags,
                                                 float* __restrict__ out,
                                                 int relu) {
  __shared__ char lds[32768];  // 8 KB per wave
  const int wave = threadIdx.x >> 6;
  const int lane = threadIdx.x & 63;
  const int wid = blockIdx.x * 4 + wave;
  if (wid >= N_NODES / 16) return;  // 6250 waves x 16 rows = 100000 exactly
  const int n0 = wid * 16;
  const int xf = resolve_f32(x_sel, flags), wf = flags[3];
  const int MAP = flags[4];
  char* myl = lds + wave * 8192;
  if (MAP == 0)
    upd_mfma_body<0>(x, xf, agg, rowptr, wsh, bupd, wf, bias, out, relu, n0, lane, myl);
  else if (MAP == 1)
    upd_mfma_body<1>(x, xf, agg, rowptr, wsh, bupd, wf, bias, out, relu, n0, lane, myl);
  else
    upd_f32_body(x, xf, agg, rowptr, W, wf, bupd, bias, out, relu, n0, lane, myl);
}

// ---------------------------------------------------------------- host
extern "C" void kernel_launch(void* const* d_in, const int* in_sizes, int n_in,
                              void* d_out, int out_size, void* d_ws, size_t ws_size,
                              hipStream_t stream) {
  const void* x   = d_in[0];
  const int*  ei  = (const int*)d_in[1];
  const void* ea  = d_in[2];
  const void* wm1 = d_in[3];
  const void* bm1 = d_in[4];
  const void* wu1 = d_in[5];
  const void* bu1 = d_in[6];
  const void* bi1 = d_in[7];
  const void* wm2 = d_in[8];
  const void* bm2 = d_in[9];
  const void* wu2 = d_in[10];
  const void* bu2 = d_in[11];
  const void* bi2 = d_in[12];
  float* out = (float*)d_out;

  // Workspace: flags | cnt | fill | rowptr | sev | agg | ybf | wsh1 | wsh2.
  char* base = (char*)d_ws;
  size_t off = 0;
  auto alloc = [&](size_t b) { size_t o = off; off += (b + 255) & ~(size_t)255; return o; };
  size_t flags_o = alloc(32);
  size_t cnt_o   = alloc((size_t)N_NODES * 4);
  size_t fill_o  = alloc((size_t)N_NODES * 4);
  size_t zero_end = off;                       // memset covers flags|cnt|fill only
  size_t rowp_o  = alloc((size_t)(N_NODES + 1) * 4);
  size_t sev_o   = alloc((size_t)N_EDGES * 8);
  size_t agg_o   = alloc((size_t)N_NODES * CH * 4);
  size_t y_o     = alloc((size_t)N_NODES * CH * 2);   // packed bf16
  size_t wsh1_o  = alloc((size_t)4096 * 8 * 2);       // 64 KB frag-ordered W
  size_t wsh2_o  = alloc((size_t)4096 * 8 * 2);
  (void)ws_size; (void)n_in; (void)in_sizes; (void)out_size;

  int*    flags = (int*)(base + flags_o);
  int*    cntp  = (int*)(base + cnt_o);
  int*    fillp = (int*)(base + fill_o);
  int*    rowp  = (int*)(base + rowp_o);
  int2*   sevp  = (int2*)(base + sev_o);
  float*  aggp  = (float*)(base + agg_o);
  uint*   ybfp  = (uint*)(base + y_o);
  ushort* wsh1  = (ushort*)(base + wsh1_o);
  ushort* wsh2  = (ushort*)(base + wsh2_o);
  float*  hp    = out;                  // layer-1 output (f32) lives in d_out

  hipMemsetAsync(base, 0, zero_end, stream);
  detect_kernel<<<1, 256, 0, stream>>>(ei, (const ushort*)x, (const ushort*)ea,
                                       (const ushort*)wm1, flags);
  mfma_probe<<<1, 64, 0, stream>>>(flags);
  count_kernel<<<(N_EDGES + 255) / 256, 256, 0, stream>>>(ei, flags, cntp);
  scan_kernel<<<1, 1024, 0, stream>>>(cntp, rowp);
  scatter_kernel<<<(N_EDGES + 255) / 256, 256, 0, stream>>>(ei, flags, rowp, fillp, sevp);
  wshuf_build<<<16, 256, 0, stream>>>(wu1, flags, wsh1);
  wshuf_build<<<16, 256, 0, stream>>>(wu2, flags, wsh2);

  const int ggrid = N_NODES / (4 * NPW);            // 3125
  const int agrid = N_NODES / 4;                    // 25000
  const int ugrid = (N_NODES / 16 + 3) / 4;         // 1563 (4 waves x 16 rows)

  // ---- layer 1
  gemm_node<<<ggrid, 256, 0, stream>>>(x, 1, wm1, bm1, flags, ybfp);
  agg_csr<<<agrid, 256, 0, stream>>>(ybfp, ea, wm1, rowp, sevp, flags, aggp);
  upd_fused<<<ugrid, 256, 0, stream>>>(x, 1, aggp, rowp, wsh1, wu1, bu1, bi1, flags, hp, 1);

  // ---- layer 2 (h is f32 in d_out -> x_sel=2 forces f32)
  gemm_node<<<ggrid, 256, 0, stream>>>(hp, 2, wm2, bm2, flags, ybfp);
  agg_csr<<<agrid, 256, 0, stream>>>(ybfp, ea, wm2, rowp, sevp, flags, aggp);
  upd_fused<<<ugrid, 256, 0, stream>>>(hp, 2, aggp, rowp, wsh2, wu2, bu2, bi2, flags, out, 0);
}

// Round 7
// 1071.866 us; speedup vs baseline: 1.3159x; 1.1587x over previous
//
#include <hip/hip_runtime.h>
#include <stdint.h>

#define N_NODES 100000
#define N_EDGES 1600000
#define CH 128
#define EDGE_DIM 16
#define KUPD 256
#define NPW 8

typedef __attribute__((ext_vector_type(8))) short short8v;   // 8 bf16 (4 VGPRs)
typedef __attribute__((ext_vector_type(4))) float f32x4;

__device__ __forceinline__ float bf2f(ushort u) {
  union { uint i; float f; } c; c.i = ((uint)u) << 16; return c.f;
}
__device__ __forceinline__ ushort f2bf(float f) {
  union { float f; uint i; } c; c.f = f;
  return (ushort)((c.i + 0x7FFFu + ((c.i >> 16) & 1u)) >> 16);
}
__device__ __forceinline__ float ldf(const void* p, int f32, size_t i) {
  return f32 ? ((const float*)p)[i] : bf2f(((const ushort*)p)[i]);
}
__device__ __forceinline__ float2 ld2(const void* p, int f32, size_t pi) {
  if (f32) return ((const float2*)p)[pi];
  uint u = ((const uint*)p)[pi];
  return make_float2(bf2f((ushort)(u & 0xFFFF)), bf2f((ushort)(u >> 16)));
}
__device__ __forceinline__ float4 ld4(const void* p, int f32, size_t qi) {
  if (f32) return ((const float4*)p)[qi];
  uint2 u = ((const uint2*)p)[qi];
  float4 r;
  r.x = bf2f((ushort)(u.x & 0xFFFF)); r.y = bf2f((ushort)(u.x >> 16));
  r.z = bf2f((ushort)(u.y & 0xFFFF)); r.w = bf2f((ushort)(u.y >> 16));
  return r;
}
// x_sel: 0 = force bf16, 1 = use detected x flag, 2 = force f32
__device__ __forceinline__ int resolve_f32(int x_sel, const int* flags) {
  return (x_sel == 2) ? 1 : (x_sel == 1 ? flags[1] : 0);
}
// MFMA A/B k-mapping candidates. g = lane>>4, j = frag element 0..7.
// MAP0 (interleaved), MAP1 (contiguous). Verified at runtime by mfma_probe.
__device__ __forceinline__ int kmap(int MAP, int g, int j, int step) {
  return MAP ? (step * 32 + 8 * g + j)
             : (step * 32 + 16 * (j >> 2) + 4 * g + (j & 3));
}

// ---------------------------------------------------------------- runtime layout/dtype detection
// flags[0]=1 -> edge_index int32 [2,E]. flags[1..3]=1 -> x / edge_attr / weights are f32.
// flags[4] = MFMA k-mapping (0/1) or 2 = no candidate verified -> f32 fallback.
__global__ __launch_bounds__(256) void detect_kernel(const int* __restrict__ ei,
                                                     const ushort* __restrict__ xu,
                                                     const ushort* __restrict__ eau,
                                                     const ushort* __restrict__ wu,
                                                     int* __restrict__ flags) {
  int any = 0, fx = 0, fe = 0, fw = 0;
  for (int i = threadIdx.x; i < 4096; i += 256) any |= ei[2 * i + 1];
  for (int i = threadIdx.x; i < 16384; i += 256) {
    fx |= (((xu[2 * i] >> 7) & 0xFF) == 0xFF);
    fe |= (((eau[2 * i] >> 7) & 0xFF) == 0xFF);
  }
  for (int i = threadIdx.x; i < 8192; i += 256) {
    fw |= (((wu[2 * i] >> 7) & 0xFF) == 0xFF);
  }
  if (any) atomicOr(flags + 0, 1);
  if (fx)  atomicOr(flags + 1, 1);
  if (fe)  atomicOr(flags + 2, 1);
  if (fw)  atomicOr(flags + 3, 1);
}

// ---------------------------------------------------------------- MFMA layout self-verification (R6, verified live)
__global__ __launch_bounds__(64) void mfma_probe(int* __restrict__ flags) {
  __shared__ ushort A[16 * 32];
  __shared__ ushort B[32 * 16];
  const int lane = threadIdx.x;
  for (int idx = lane; idx < 512; idx += 64) {
    int i = idx >> 5, k = idx & 31;
    A[idx] = f2bf((float)((i * 5 + k * 3) % 13 - 6));
    int k2 = idx >> 4, c = idx & 15;
    B[idx] = f2bf((float)((k2 * 7 + c * 11) % 15 - 7));
  }
  __syncthreads();
  const int col = lane & 15, g = lane >> 4;
  float cr[4];
#pragma unroll
  for (int r = 0; r < 4; ++r) {
    int row = g * 4 + r;
    float s = 0.f;
    for (int k = 0; k < 32; ++k) s += bf2f(A[row * 32 + k]) * bf2f(B[k * 16 + col]);
    cr[r] = s;
  }
  int win = 2;
  for (int MAP = 0; MAP < 2; ++MAP) {
    if (win != 2) break;
    short8v a, b;
#pragma unroll
    for (int j = 0; j < 8; ++j) {
      int k = kmap(MAP, g, j, 0);
      a[j] = (short)A[(lane & 15) * 32 + k];
      b[j] = (short)B[k * 16 + col];
    }
    f32x4 z = {0.f, 0.f, 0.f, 0.f};
    f32x4 d = __builtin_amdgcn_mfma_f32_16x16x32_bf16(a, b, z, 0, 0, 0);
    int good = 1;
#pragma unroll
    for (int r = 0; r < 4; ++r) good &= (d[r] == cr[r]);
    if (__all(good)) win = MAP;
  }
  if (lane == 0) flags[4] = win;
}

__device__ __forceinline__ void load_edge(const int* __restrict__ ei, int i32, int e,
                                          int& s, int& d) {
  if (i32) { s = ei[e]; d = ei[N_EDGES + e]; }
  else     { s = ei[2 * e]; d = ei[2 * N_EDGES + 2 * e]; }
  s = min(max(s, 0), N_NODES - 1);
  d = min(max(d, 0), N_NODES - 1);
}

// ---------------------------------------------------------------- degree count (dst only)
__global__ __launch_bounds__(256) void count_kernel(const int* __restrict__ ei,
                                                    const int* __restrict__ flags,
                                                    int* __restrict__ cnt) {
  int e = blockIdx.x * 256 + threadIdx.x;
  if (e >= N_EDGES) return;
  int d = flags[0] ? ei[N_EDGES + e] : ei[2 * N_EDGES + 2 * e];
  d = min(max(d, 0), N_NODES - 1);
  atomicAdd(&cnt[d], 1);
}

// ---------------------------------------------------------------- exclusive prefix scan of cnt -> rowptr
__global__ __launch_bounds__(1024) void scan_kernel(const int* __restrict__ cnt,
                                                    int* __restrict__ rowptr) {
  __shared__ int part[1024];
  const int t = threadIdx.x;
  const int CHUNK = (N_NODES + 1023) / 1024;  // 98
  int base = t * CHUNK;
  int lim = min(base + CHUNK, N_NODES);
  int s = 0;
  for (int i = base; i < lim; ++i) s += cnt[i];
  part[t] = s;
  __syncthreads();
  for (int off = 1; off < 1024; off <<= 1) {
    int v = (t >= off) ? part[t - off] : 0;
    __syncthreads();
    part[t] += v;
    __syncthreads();
  }
  int excl = (t == 0) ? 0 : part[t - 1];
  for (int i = base; i < lim; ++i) { rowptr[i] = excl; excl += cnt[i]; }
  if (t == 1023) rowptr[N_NODES] = part[1023];
}

// ---------------------------------------------------------------- CSR scatter: {src, eid} sorted by dst
__global__ __launch_bounds__(256) void scatter_kernel(const int* __restrict__ ei,
                                                      const int* __restrict__ flags,
                                                      const int* __restrict__ rowptr,
                                                      int* __restrict__ fill,
                                                      int2* __restrict__ sev) {
  int e = blockIdx.x * 256 + threadIdx.x;
  if (e >= N_EDGES) return;
  int s, d;
  load_edge(ei, flags[0], e, s, d);
  int pos = atomicAdd(&fill[d], 1);
  sev[rowptr[d] + pos] = make_int2(s, e);
}

// ---------------------------------------------------------------- unified W pre-shuffle (ALL 4 weight mats, 1 launch)
// wsh[ts*512 + lane*8 + j] = bf16(W[kmap(g,j,step)][t*16+col]); ts = t*NSTEP+step.
// upd W (K=256): 8 tiles x 8 steps; msg W (K=128 part): 8 tiles x 4 steps.
__global__ __launch_bounds__(256) void wshuf_all(const void* __restrict__ wu1,
                                                 const void* __restrict__ wu2,
                                                 const void* __restrict__ wm1,
                                                 const void* __restrict__ wm2,
                                                 const int* __restrict__ flags,
                                                 ushort* __restrict__ ou1,
                                                 ushort* __restrict__ ou2,
                                                 ushort* __restrict__ om1,
                                                 ushort* __restrict__ om2) {
  const int MAP = flags[4], wf = flags[3];
  if (MAP == 2) return;
  int tid = blockIdx.x * 256 + threadIdx.x;  // 192 groups * 64 = 12288
  if (tid >= 12288) return;
  int gg = tid >> 6, lane = tid & 63;
  const void* W; ushort* dst; int t, step, ts;
  if (gg < 64)       { W = wu1; dst = ou1; int l = gg;       t = l >> 3; step = l & 7; ts = t * 8 + step; }
  else if (gg < 128) { W = wu2; dst = ou2; int l = gg - 64;  t = l >> 3; step = l & 7; ts = t * 8 + step; }
  else if (gg < 160) { W = wm1; dst = om1; int l = gg - 128; t = l >> 2; step = l & 3; ts = t * 4 + step; }
  else               { W = wm2; dst = om2; int l = gg - 160; t = l >> 2; step = l & 3; ts = t * 4 + step; }
  int col = t * 16 + (lane & 15), g = lane >> 4;
#pragma unroll
  for (int j = 0; j < 8; ++j) {
    int k = kmap(MAP, g, j, step);
    dst[(size_t)ts * 512 + lane * 8 + j] = f2bf(ldf(W, wf, (size_t)k * CH + col));
  }
}

// ---------------------------------------------------------------- node GEMM y = x @ Wm[0:128] + b on MFMA
// One wave = 16 rows, K=128: 4 steps x 8 col-tiles = 32 MFMAs. A staged bf16 in
// per-wave 4KB LDS (XOR swizzle). Epilogue writes ybf in FRAG-PAIR layout:
// slot u*16+col of row n holds channels (32u+col, 32u+16+col) -- the pair the
// lane already owns (tiles 2u, 2u+1), so no cross-lane repack. agg_csr consumes
// via matching cmap. No norm/relu here (relu happens after +z in agg).
template <int MAP>
__device__ __forceinline__ void gemm_mfma_body(const void* __restrict__ x, int xf,
                                               const ushort* __restrict__ wshm,
                                               const void* __restrict__ bmsg, int wf,
                                               uint* __restrict__ ybf,
                                               int n0, int lane, char* lds) {
  const int srow = lane >> 2;
  const int q = lane & 3;
  {
    uint sw = (uint)((srow & 7) << 4);
#pragma unroll
    for (int i = 0; i < 8; ++i) {
      int qi = q + 4 * i;  // float4 index within 128-ch row
      float4 v = ld4(x, xf, (size_t)(n0 + srow) * 32 + qi);
      uint2 pk;
      pk.x = (uint)f2bf(v.x) | ((uint)f2bf(v.y) << 16);
      pk.y = (uint)f2bf(v.z) | ((uint)f2bf(v.w) << 16);
      *(uint2*)(lds + (((uint)srow * 256u + (uint)qi * 8u) ^ sw)) = pk;
    }
  }
  asm volatile("s_waitcnt lgkmcnt(0)" ::: "memory");
  __builtin_amdgcn_sched_barrier(0);

  const int col = lane & 15, g = lane >> 4;
  const int ra = lane & 15;
  const uint asw = (uint)((ra & 7) << 4);
  f32x4 acc[8];
#pragma unroll
  for (int t = 0; t < 8; ++t) acc[t] = (f32x4){0.f, 0.f, 0.f, 0.f};

#pragma unroll
  for (int step = 0; step < 4; ++step) {
    short8v a;
    if (MAP) {
      uint byte = (uint)ra * 256u + (uint)(step * 32 + 8 * g) * 2u;
      *(uint4*)&a = *(const uint4*)(lds + (byte ^ asw));
    } else {
      uint b0 = (uint)ra * 256u + (uint)(step * 32 + 4 * g) * 2u;
      uint b1 = b0 + 32u;
      uint2 lo = *(const uint2*)(lds + (b0 ^ asw));
      uint2 hi = *(const uint2*)(lds + (b1 ^ asw));
      uint4 pk = make_uint4(lo.x, lo.y, hi.x, hi.y);
      *(uint4*)&a = pk;
    }
#pragma unroll
    for (int t = 0; t < 8; ++t) {
      short8v b = *(const short8v*)(wshm + ((size_t)(t * 4 + step) * 512 + lane * 8));
      acc[t] = __builtin_amdgcn_mfma_f32_16x16x32_bf16(a, b, acc[t], 0, 0, 0);
    }
  }

#pragma unroll
  for (int u = 0; u < 4; ++u) {
    float b0v = ldf(bmsg, wf, u * 32 + col);        // ch of tile 2u  : 32u+col
    float b1v = ldf(bmsg, wf, u * 32 + 16 + col);   // ch of tile 2u+1: 32u+16+col
#pragma unroll
    for (int r = 0; r < 4; ++r) {
      uint pk = (uint)f2bf(acc[2 * u][r] + b0v) | ((uint)f2bf(acc[2 * u + 1][r] + b1v) << 16);
      ybf[(uint)(n0 + g * 4 + r) * 64u + (uint)(u * 16 + col)] = pk;
    }
  }
}

// f32 fallback: canonical ybf pairing (2*lane, 2*lane+1); 2 chunks of 8 rows.
__device__ __forceinline__ void gemm_f32_body(const void* __restrict__ x, int xf,
                                              const void* __restrict__ W, int wf,
                                              const void* __restrict__ b,
                                              uint* __restrict__ ybf,
                                              int wave_n0, int lane, char* ldsc) {
  float* xs = (float*)ldsc;  // [8][128] per-wave 4KB
  for (int c = 0; c < 2; ++c) {
    int n0 = wave_n0 + c * 8;
#pragma unroll
    for (int r = 0; r < NPW; ++r) {
      float2 a = ld2(x, xf, (size_t)(n0 + r) * 64 + lane);
      xs[r * 128 + 2 * lane]     = a.x;
      xs[r * 128 + 2 * lane + 1] = a.y;
    }
    asm volatile("s_waitcnt lgkmcnt(0)" ::: "memory");
    __builtin_amdgcn_sched_barrier(0);
    float acc0[NPW], acc1[NPW];
#pragma unroll
    for (int r = 0; r < NPW; ++r) { acc0[r] = 0.f; acc1[r] = 0.f; }
#pragma unroll 4
    for (int k = 0; k < CH; k += 2) {
      float2 w0 = ld2(W, wf, (size_t)k * 64 + lane);
      float2 w1 = ld2(W, wf, (size_t)(k + 1) * 64 + lane);
#pragma unroll
      for (int r = 0; r < NPW; ++r) {
        float2 a = *(const float2*)&xs[r * 128 + k];
        acc0[r] += a.x * w0.x;
        acc1[r] += a.x * w0.y;
        acc0[r] += a.y * w1.x;
        acc1[r] += a.y * w1.y;
      }
    }
    float2 bb = ld2(b, wf, lane);
#pragma unroll
    for (int r = 0; r < NPW; ++r) {
      uint pk = (uint)f2bf(acc0[r] + bb.x) | ((uint)f2bf(acc1[r] + bb.y) << 16);
      ybf[(uint)(n0 + r) * 64u + (uint)lane] = pk;
    }
  }
}

__global__ __launch_bounds__(256) void gemm_node(const void* __restrict__ x, int x_sel,
                                                 const ushort* __restrict__ wshm,
                                                 const void* __restrict__ W,
                                                 const void* __restrict__ b,
                                                 const int* __restrict__ flags,
                                                 uint* __restrict__ ybf) {
  __shared__ char lds[16384];  // 4 KB per wave
  const int wave = threadIdx.x >> 6;
  const int lane = threadIdx.x & 63;
  const int wid = blockIdx.x * 4 + wave;
  if (wid >= N_NODES / 16) return;
  const int n0 = wid * 16;
  const int xf = resolve_f32(x_sel, flags), wf = flags[3];
  const int MAP = flags[4];
  char* myl = lds + wave * 4096;
  if (MAP == 0)      gemm_mfma_body<0>(x, xf, wshm, b, wf, ybf, n0, lane, myl);
  else if (MAP == 1) gemm_mfma_body<1>(x, xf, wshm, b, wf, ybf, n0, lane, myl);
  else               gemm_f32_body(x, xf, W, wf, b, ybf, n0, lane, myl);
}

// ---------------------------------------------------------------- CSR aggregation (R4 body + cmap):
// lane's channel pair follows ybf's layout: frag-pair (32u+col, +16) when MFMA
// is live, canonical (2l, 2l+1) on fallback. Per-channel f32 accumulation order
// is unchanged -> numerics identical; only lane<->channel assignment moves.
__global__ __launch_bounds__(256, 4) void agg_csr(const uint* __restrict__ ybf,
                                                  const void* __restrict__ ea,
                                                  const void* __restrict__ W,
                                                  const int* __restrict__ rowptr,
                                                  const int2* __restrict__ sev,
                                                  const int* __restrict__ flags,
                                                  float* __restrict__ agg) {
  const int wave = threadIdx.x >> 6;
  const int lane = threadIdx.x & 63;
  const int ef = flags[2], wf = flags[3], MAP = flags[4];
  const int c0 = (MAP < 2) ? (32 * (lane >> 4) + (lane & 15)) : (2 * lane);
  const int c1 = (MAP < 2) ? (c0 + 16) : (c0 + 1);

  float wex[EDGE_DIM], wey[EDGE_DIM];
#pragma unroll
  for (int k = 0; k < EDGE_DIM; ++k) {
    wex[k] = ldf(W, wf, (size_t)(CH + k) * CH + c0);
    wey[k] = ldf(W, wf, (size_t)(CH + k) * CH + c1);
  }

  const int n = blockIdx.x * 4 + wave;  // grid = N/4 exactly
  const int beg = rowptr[n], end = rowptr[n + 1];
  float acc0 = 0.f, acc1 = 0.f;

  auto edge = [&](uint yu, float4 q0, float4 q1, float4 q2, float4 q3) {
    float av[16] = {q0.x, q0.y, q0.z, q0.w, q1.x, q1.y, q1.z, q1.w,
                    q2.x, q2.y, q2.z, q2.w, q3.x, q3.y, q3.z, q3.w};
    float z0 = 0.f, z1 = 0.f;
#pragma unroll
    for (int k = 0; k < EDGE_DIM; ++k) {
      z0 += av[k] * wex[k];
      z1 += av[k] * wey[k];
    }
    acc0 += fmaxf(bf2f((ushort)(yu & 0xFFFF)) + z0, 0.f);
    acc1 += fmaxf(bf2f((ushort)(yu >> 16)) + z1, 0.f);
  };

  int j = beg;
  for (; j + 4 <= end; j += 4) {
    int2 p0 = sev[j], p1 = sev[j + 1], p2 = sev[j + 2], p3 = sev[j + 3];
    int s0 = __builtin_amdgcn_readfirstlane(p0.x), e0 = __builtin_amdgcn_readfirstlane(p0.y);
    int s1 = __builtin_amdgcn_readfirstlane(p1.x), e1 = __builtin_amdgcn_readfirstlane(p1.y);
    int s2 = __builtin_amdgcn_readfirstlane(p2.x), e2 = __builtin_amdgcn_readfirstlane(p2.y);
    int s3 = __builtin_amdgcn_readfirstlane(p3.x), e3 = __builtin_amdgcn_readfirstlane(p3.y);
    uint y0 = ybf[(size_t)s0 * 64 + lane];
    uint y1 = ybf[(size_t)s1 * 64 + lane];
    uint y2 = ybf[(size_t)s2 * 64 + lane];
    uint y3 = ybf[(size_t)s3 * 64 + lane];
    float4 a00 = ld4(ea, ef, (size_t)e0 * 4 + 0);
    float4 a01 = ld4(ea, ef, (size_t)e0 * 4 + 1);
    float4 a02 = ld4(ea, ef, (size_t)e0 * 4 + 2);
    float4 a03 = ld4(ea, ef, (size_t)e0 * 4 + 3);
    float4 a10 = ld4(ea, ef, (size_t)e1 * 4 + 0);
    float4 a11 = ld4(ea, ef, (size_t)e1 * 4 + 1);
    float4 a12 = ld4(ea, ef, (size_t)e1 * 4 + 2);
    float4 a13 = ld4(ea, ef, (size_t)e1 * 4 + 3);
    float4 a20 = ld4(ea, ef, (size_t)e2 * 4 + 0);
    float4 a21 = ld4(ea, ef, (size_t)e2 * 4 + 1);
    float4 a22 = ld4(ea, ef, (size_t)e2 * 4 + 2);
    float4 a23 = ld4(ea, ef, (size_t)e2 * 4 + 3);
    float4 a30 = ld4(ea, ef, (size_t)e3 * 4 + 0);
    float4 a31 = ld4(ea, ef, (size_t)e3 * 4 + 1);
    float4 a32 = ld4(ea, ef, (size_t)e3 * 4 + 2);
    float4 a33 = ld4(ea, ef, (size_t)e3 * 4 + 3);
    edge(y0, a00, a01, a02, a03);
    edge(y1, a10, a11, a12, a13);
    edge(y2, a20, a21, a22, a23);
    edge(y3, a30, a31, a32, a33);
  }
  for (; j < end; ++j) {
    int2 p = sev[j];
    int s = __builtin_amdgcn_readfirstlane(p.x), e = __builtin_amdgcn_readfirstlane(p.y);
    uint yu = ybf[(size_t)s * 64 + lane];
    float4 q0 = ld4(ea, ef, (size_t)e * 4 + 0);
    float4 q1 = ld4(ea, ef, (size_t)e * 4 + 1);
    float4 q2 = ld4(ea, ef, (size_t)e * 4 + 2);
    float4 q3 = ld4(ea, ef, (size_t)e * 4 + 3);
    edge(yu, q0, q1, q2, q3);
  }
  agg[(size_t)n * CH + c0] = acc0;
  agg[(size_t)n * CH + c1] = acc1;
}

// ---------------------------------------------------------------- update GEMM on MFMA + fused norm (R6, unchanged)
template <int MAP>
__device__ __forceinline__ void upd_mfma_body(const void* __restrict__ x, int xf,
                                              const float* __restrict__ agg,
                                              const int* __restrict__ rowptr,
                                              const ushort* __restrict__ wsh,
                                              const void* __restrict__ bupd, int wf,
                                              const void* __restrict__ bias,
                                              float* __restrict__ out, int relu,
                                              int n0, int lane, char* lds) {
  const int srow = lane >> 2;
  const int q = lane & 3;
  {
    int c = rowptr[n0 + srow + 1] - rowptr[n0 + srow];
    float inv = 1.f / (float)(c > 1 ? c : 1);
    uint sw = (uint)((srow & 7) << 4);
#pragma unroll
    for (int i = 0; i < 8; ++i) {
      int qi = q + 4 * i;
      float4 v = ld4(x, xf, (size_t)(n0 + srow) * 32 + qi);
      uint2 pk;
      pk.x = (uint)f2bf(v.x) | ((uint)f2bf(v.y) << 16);
      pk.y = (uint)f2bf(v.z) | ((uint)f2bf(v.w) << 16);
      *(uint2*)(lds + (((uint)srow * 512u + (uint)qi * 8u) ^ sw)) = pk;
      float4 w = ((const float4*)agg)[(size_t)(n0 + srow) * 32 + qi];
      uint2 pk2;
      pk2.x = (uint)f2bf(w.x * inv) | ((uint)f2bf(w.y * inv) << 16);
      pk2.y = (uint)f2bf(w.z * inv) | ((uint)f2bf(w.w * inv) << 16);
      *(uint2*)(lds + (((uint)srow * 512u + 256u + (uint)qi * 8u) ^ sw)) = pk2;
    }
  }
  asm volatile("s_waitcnt lgkmcnt(0)" ::: "memory");
  __builtin_amdgcn_sched_barrier(0);

  const int col = lane & 15, g = lane >> 4;
  const int ra = lane & 15;
  const uint asw = (uint)((ra & 7) << 4);
  f32x4 acc[8];
#pragma unroll
  for (int t = 0; t < 8; ++t) acc[t] = (f32x4){0.f, 0.f, 0.f, 0.f};

#pragma unroll
  for (int step = 0; step < 8; ++step) {
    short8v a;
    if (MAP) {
      uint byte = (uint)ra * 512u + (uint)(step * 32 + 8 * g) * 2u;
      *(uint4*)&a = *(const uint4*)(lds + (byte ^ asw));
    } else {
      uint b0 = (uint)ra * 512u + (uint)(step * 32 + 4 * g) * 2u;
      uint b1 = b0 + 32u;
      uint2 lo = *(const uint2*)(lds + (b0 ^ asw));
      uint2 hi = *(const uint2*)(lds + (b1 ^ asw));
      uint4 pk = make_uint4(lo.x, lo.y, hi.x, hi.y);
      *(uint4*)&a = pk;
    }
#pragma unroll
    for (int t = 0; t < 8; ++t) {
      short8v b = *(const short8v*)(wsh + ((size_t)(t * 8 + step) * 512 + lane * 8));
      acc[t] = __builtin_amdgcn_mfma_f32_16x16x32_bf16(a, b, acc[t], 0, 0, 0);
    }
  }

  float bu[8], bi[8];
#pragma unroll
  for (int t = 0; t < 8; ++t) {
    bu[t] = ldf(bupd, wf, t * 16 + col);
    bi[t] = ldf(bias, wf, t * 16 + col);
  }
  float raw[8][4];
  float ss[4] = {0.f, 0.f, 0.f, 0.f};
#pragma unroll
  for (int t = 0; t < 8; ++t)
#pragma unroll
    for (int r = 0; r < 4; ++r) {
      float v = acc[t][r] + bu[t];
      raw[t][r] = v;
      ss[r] += v * v;
    }
#pragma unroll
  for (int r = 0; r < 4; ++r)
#pragma unroll
    for (int o = 1; o < 16; o <<= 1) ss[r] += __shfl_xor(ss[r], o);
#pragma unroll
  for (int r = 0; r < 4; ++r) {
    float inv = 1.0f / fmaxf(sqrtf(ss[r]), 1e-12f);
    int row = g * 4 + r;
#pragma unroll
    for (int t = 0; t < 8; ++t) {
      float o = raw[t][r] * inv + bi[t];
      if (relu) o = fmaxf(o, 0.f);
      out[(size_t)(n0 + row) * CH + t * 16 + col] = o;
    }
  }
}

__device__ __forceinline__ void upd_f32_body(const void* __restrict__ x, int xf,
                                             const float* __restrict__ agg,
                                             const int* __restrict__ rowptr,
                                             const void* __restrict__ W, int wf,
                                             const void* __restrict__ bupd,
                                             const void* __restrict__ bias,
                                             float* __restrict__ out, int relu,
                                             int wave_n0, int lane, char* ldsc) {
  float* xs = (float*)ldsc;  // [8][256] f32 = 8 KB per-wave slice
  for (int c = 0; c < 2; ++c) {
    int n0 = wave_n0 + c * 8;
#pragma unroll
    for (int r = 0; r < NPW; ++r) {
      int n = n0 + r;
      float2 a = ld2(x, xf, (size_t)n * 64 + lane);
      xs[r * 256 + 2 * lane]     = a.x;
      xs[r * 256 + 2 * lane + 1] = a.y;
      int cd = rowptr[n + 1] - rowptr[n];
      float inv = 1.f / (float)(cd > 1 ? cd : 1);
      xs[r * 256 + CH + 2 * lane]     = agg[(size_t)n * CH + 2 * lane] * inv;
      xs[r * 256 + CH + 2 * lane + 1] = agg[(size_t)n * CH + 2 * lane + 1] * inv;
    }
    asm volatile("s_waitcnt lgkmcnt(0)" ::: "memory");
    __builtin_amdgcn_sched_barrier(0);

    float acc0[NPW], acc1[NPW];
#pragma unroll
    for (int r = 0; r < NPW; ++r) { acc0[r] = 0.f; acc1[r] = 0.f; }
#pragma unroll 4
    for (int k = 0; k < KUPD; k += 2) {
      float2 w0 = ld2(W, wf, (size_t)k * 64 + lane);
      float2 w1 = ld2(W, wf, (size_t)(k + 1) * 64 + lane);
#pragma unroll
      for (int r = 0; r < NPW; ++r) {
        float2 a = *(const float2*)&xs[r * 256 + k];
        acc0[r] += a.x * w0.x;
        acc1[r] += a.x * w0.y;
        acc0[r] += a.y * w1.x;
        acc1[r] += a.y * w1.y;
      }
    }
    float2 b  = ld2(bupd, wf, lane);
    float2 bi = ld2(bias, wf, lane);
#pragma unroll
    for (int r = 0; r < NPW; ++r) {
      float r0 = acc0[r] + b.x;
      float r1 = acc1[r] + b.y;
      float sq = r0 * r0 + r1 * r1;
#pragma unroll
      for (int o = 32; o; o >>= 1) sq += __shfl_xor(sq, o);
      float innv = 1.0f / fmaxf(sqrtf(sq), 1e-12f);
      float o0 = r0 * innv + bi.x;
      float o1 = r1 * innv + bi.y;
      if (relu) { o0 = fmaxf(o0, 0.f); o1 = fmaxf(o1, 0.f); }
      size_t n = (size_t)(n0 + r);
      out[n * CH + 2 * lane]     = o0;
      out[n * CH + 2 * lane + 1] = o1;
    }
  }
}

__global__ __launch_bounds__(256) void upd_fused(const void* __restrict__ x, int x_sel,
                                                 const float* __restrict__ agg,
                                                 const int* __restrict__ rowptr,
                                                 const ushort* __restrict__ wsh,
                                                 const void* __restrict__ W,
                                                 const void* __restrict__ bupd,
                                                 const void* __restrict__ bias,
                                                 const int* __restrict__ flags,
                                                 float* __restrict__ out,
                                                 int relu) {
  __shared__ char lds[32768];  // 8 KB per wave
  const int wave = threadIdx.x >> 6;
  const int lane = threadIdx.x & 63;
  const int wid = blockIdx.x * 4 + wave;
  if (wid >= N_NODES / 16) return;
  const int n0 = wid * 16;
  const int xf = resolve_f32(x_sel, flags), wf = flags[3];
  const int MAP = flags[4];
  char* myl = lds + wave * 8192;
  if (MAP == 0)
    upd_mfma_body<0>(x, xf, agg, rowptr, wsh, bupd, wf, bias, out, relu, n0, lane, myl);
  else if (MAP == 1)
    upd_mfma_body<1>(x, xf, agg, rowptr, wsh, bupd, wf, bias, out, relu, n0, lane, myl);
  else
    upd_f32_body(x, xf, agg, rowptr, W, wf, bupd, bias, out, relu, n0, lane, myl);
}

// ---------------------------------------------------------------- host
extern "C" void kernel_launch(void* const* d_in, const int* in_sizes, int n_in,
                              void* d_out, int out_size, void* d_ws, size_t ws_size,
                              hipStream_t stream) {
  const void* x   = d_in[0];
  const int*  ei  = (const int*)d_in[1];
  const void* ea  = d_in[2];
  const void* wm1 = d_in[3];
  const void* bm1 = d_in[4];
  const void* wu1 = d_in[5];
  const void* bu1 = d_in[6];
  const void* bi1 = d_in[7];
  const void* wm2 = d_in[8];
  const void* bm2 = d_in[9];
  const void* wu2 = d_in[10];
  const void* bu2 = d_in[11];
  const void* bi2 = d_in[12];
  float* out = (float*)d_out;

  char* base = (char*)d_ws;
  size_t off = 0;
  auto alloc = [&](size_t b) { size_t o = off; off += (b + 255) & ~(size_t)255; return o; };
  size_t flags_o = alloc(32);
  size_t cnt_o   = alloc((size_t)N_NODES * 4);
  size_t fill_o  = alloc((size_t)N_NODES * 4);
  size_t zero_end = off;                       // memset covers flags|cnt|fill only
  size_t rowp_o  = alloc((size_t)(N_NODES + 1) * 4);
  size_t sev_o   = alloc((size_t)N_EDGES * 8);
  size_t agg_o   = alloc((size_t)N_NODES * CH * 4);
  size_t y_o     = alloc((size_t)N_NODES * CH * 2);   // packed bf16
  size_t wsh1_o  = alloc((size_t)4096 * 8 * 2);       // upd W1, 64 KB
  size_t wsh2_o  = alloc((size_t)4096 * 8 * 2);       // upd W2
  size_t wshm1_o = alloc((size_t)2048 * 8 * 2);       // msg W1[0:128], 32 KB
  size_t wshm2_o = alloc((size_t)2048 * 8 * 2);       // msg W2[0:128]
  (void)ws_size; (void)n_in; (void)in_sizes; (void)out_size;

  int*    flags = (int*)(base + flags_o);
  int*    cntp  = (int*)(base + cnt_o);
  int*    fillp = (int*)(base + fill_o);
  int*    rowp  = (int*)(base + rowp_o);
  int2*   sevp  = (int2*)(base + sev_o);
  float*  aggp  = (float*)(base + agg_o);
  uint*   ybfp  = (uint*)(base + y_o);
  ushort* wsh1  = (ushort*)(base + wsh1_o);
  ushort* wsh2  = (ushort*)(base + wsh2_o);
  ushort* wshm1 = (ushort*)(base + wshm1_o);
  ushort* wshm2 = (ushort*)(base + wshm2_o);
  float*  hp    = out;                  // layer-1 output (f32) lives in d_out

  hipMemsetAsync(base, 0, zero_end, stream);
  detect_kernel<<<1, 256, 0, stream>>>(ei, (const ushort*)x, (const ushort*)ea,
                                       (const ushort*)wm1, flags);
  mfma_probe<<<1, 64, 0, stream>>>(flags);
  count_kernel<<<(N_EDGES + 255) / 256, 256, 0, stream>>>(ei, flags, cntp);
  scan_kernel<<<1, 1024, 0, stream>>>(cntp, rowp);
  scatter_kernel<<<(N_EDGES + 255) / 256, 256, 0, stream>>>(ei, flags, rowp, fillp, sevp);
  wshuf_all<<<48, 256, 0, stream>>>(wu1, wu2, wm1, wm2, flags, wsh1, wsh2, wshm1, wshm2);

  const int agrid = N_NODES / 4;             // 25000
  const int wgrid = (N_NODES / 16 + 3) / 4;  // 1563 (4 waves x 16 rows)

  // ---- layer 1
  gemm_node<<<wgrid, 256, 0, stream>>>(x, 1, wshm1, wm1, bm1, flags, ybfp);
  agg_csr<<<agrid, 256, 0, stream>>>(ybfp, ea, wm1, rowp, sevp, flags, aggp);
  upd_fused<<<wgrid, 256, 0, stream>>>(x, 1, aggp, rowp, wsh1, wu1, bu1, bi1, flags, hp, 1);

  // ---- layer 2 (h is f32 in d_out -> x_sel=2 forces f32)
  gemm_node<<<wgrid, 256, 0, stream>>>(hp, 2, wshm2, wm2, bm2, flags, ybfp);
  agg_csr<<<agrid, 256, 0, stream>>>(ybfp, ea, wm2, rowp, sevp, flags, aggp);
  upd_fused<<<wgrid, 256, 0, stream>>>(hp, 2, aggp, rowp, wsh2, wu2, bu2, bi2, flags, out, 0);
}

// Round 9
// 1006.867 us; speedup vs baseline: 1.4009x; 1.0646x over previous
//
#include <hip/hip_runtime.h>
#include <stdint.h>

#define N_NODES 100000
#define N_EDGES 1600000
#define CH 128
#define EDGE_DIM 16
#define KUPD 256
#define NPW 8

typedef __attribute__((ext_vector_type(8))) short short8v;   // 8 bf16 (4 VGPRs)
typedef __attribute__((ext_vector_type(4))) float f32x4;

__device__ __forceinline__ float bf2f(ushort u) {
  union { uint i; float f; } c; c.i = ((uint)u) << 16; return c.f;
}
__device__ __forceinline__ ushort f2bf(float f) {
  union { float f; uint i; } c; c.f = f;
  return (ushort)((c.i + 0x7FFFu + ((c.i >> 16) & 1u)) >> 16);
}
__device__ __forceinline__ float ldf(const void* p, int f32, size_t i) {
  return f32 ? ((const float*)p)[i] : bf2f(((const ushort*)p)[i]);
}
__device__ __forceinline__ float2 ld2(const void* p, int f32, size_t pi) {
  if (f32) return ((const float2*)p)[pi];
  uint u = ((const uint*)p)[pi];
  return make_float2(bf2f((ushort)(u & 0xFFFF)), bf2f((ushort)(u >> 16)));
}
__device__ __forceinline__ float4 ld4(const void* p, int f32, size_t qi) {
  if (f32) return ((const float4*)p)[qi];
  uint2 u = ((const uint2*)p)[qi];
  float4 r;
  r.x = bf2f((ushort)(u.x & 0xFFFF)); r.y = bf2f((ushort)(u.x >> 16));
  r.z = bf2f((ushort)(u.y & 0xFFFF)); r.w = bf2f((ushort)(u.y >> 16));
  return r;
}
// x_sel: 0 = force bf16, 1 = use detected x flag, 2 = force f32
__device__ __forceinline__ int resolve_f32(int x_sel, const int* flags) {
  return (x_sel == 2) ? 1 : (x_sel == 1 ? flags[1] : 0);
}
// MFMA A/B k-mapping candidates. g = lane>>4, j = frag element 0..7.
// MAP0 (interleaved), MAP1 (contiguous). Verified at runtime by mfma_probe.
__device__ __forceinline__ int kmap(int MAP, int g, int j, int step) {
  return MAP ? (step * 32 + 8 * g + j)
             : (step * 32 + 16 * (j >> 2) + 4 * g + (j & 3));
}

// ---------------------------------------------------------------- runtime layout/dtype detection
// flags[0]=1 -> edge_index int32 [2,E]. flags[1..3]=1 -> x / edge_attr / weights are f32.
// flags[4] = MFMA k-mapping (0/1) or 2 = no candidate verified -> f32 fallback.
__global__ __launch_bounds__(256) void detect_kernel(const int* __restrict__ ei,
                                                     const ushort* __restrict__ xu,
                                                     const ushort* __restrict__ eau,
                                                     const ushort* __restrict__ wu,
                                                     int* __restrict__ flags) {
  int any = 0, fx = 0, fe = 0, fw = 0;
  for (int i = threadIdx.x; i < 4096; i += 256) any |= ei[2 * i + 1];
  for (int i = threadIdx.x; i < 16384; i += 256) {
    fx |= (((xu[2 * i] >> 7) & 0xFF) == 0xFF);
    fe |= (((eau[2 * i] >> 7) & 0xFF) == 0xFF);
  }
  for (int i = threadIdx.x; i < 8192; i += 256) {
    fw |= (((wu[2 * i] >> 7) & 0xFF) == 0xFF);
  }
  if (any) atomicOr(flags + 0, 1);
  if (fx)  atomicOr(flags + 1, 1);
  if (fe)  atomicOr(flags + 2, 1);
  if (fw)  atomicOr(flags + 3, 1);
}

// ---------------------------------------------------------------- MFMA layout self-verification (R6, verified live)
__global__ __launch_bounds__(64) void mfma_probe(int* __restrict__ flags) {
  __shared__ ushort A[16 * 32];
  __shared__ ushort B[32 * 16];
  const int lane = threadIdx.x;
  for (int idx = lane; idx < 512; idx += 64) {
    int i = idx >> 5, k = idx & 31;
    A[idx] = f2bf((float)((i * 5 + k * 3) % 13 - 6));
    int k2 = idx >> 4, c = idx & 15;
    B[idx] = f2bf((float)((k2 * 7 + c * 11) % 15 - 7));
  }
  __syncthreads();
  const int col = lane & 15, g = lane >> 4;
  float cr[4];
#pragma unroll
  for (int r = 0; r < 4; ++r) {
    int row = g * 4 + r;
    float s = 0.f;
    for (int k = 0; k < 32; ++k) s += bf2f(A[row * 32 + k]) * bf2f(B[k * 16 + col]);
    cr[r] = s;
  }
  int win = 2;
  for (int MAP = 0; MAP < 2; ++MAP) {
    if (win != 2) break;
    short8v a, b;
#pragma unroll
    for (int j = 0; j < 8; ++j) {
      int k = kmap(MAP, g, j, 0);
      a[j] = (short)A[(lane & 15) * 32 + k];
      b[j] = (short)B[k * 16 + col];
    }
    f32x4 z = {0.f, 0.f, 0.f, 0.f};
    f32x4 d = __builtin_amdgcn_mfma_f32_16x16x32_bf16(a, b, z, 0, 0, 0);
    int good = 1;
#pragma unroll
    for (int r = 0; r < 4; ++r) good &= (d[r] == cr[r]);
    if (__all(good)) win = MAP;
  }
  if (lane == 0) flags[4] = win;
}

__device__ __forceinline__ void load_edge(const int* __restrict__ ei, int i32, int e,
                                          int& s, int& d) {
  if (i32) { s = ei[e]; d = ei[N_EDGES + e]; }
  else     { s = ei[2 * e]; d = ei[2 * N_EDGES + 2 * e]; }
  s = min(max(s, 0), N_NODES - 1);
  d = min(max(d, 0), N_NODES - 1);
}

// ---------------------------------------------------------------- degree count (dst only)
__global__ __launch_bounds__(256) void count_kernel(const int* __restrict__ ei,
                                                    const int* __restrict__ flags,
                                                    int* __restrict__ cnt) {
  int e = blockIdx.x * 256 + threadIdx.x;
  if (e >= N_EDGES) return;
  int d = flags[0] ? ei[N_EDGES + e] : ei[2 * N_EDGES + 2 * e];
  d = min(max(d, 0), N_NODES - 1);
  atomicAdd(&cnt[d], 1);
}

// ---------------------------------------------------------------- exclusive prefix scan of cnt -> rowptr
__global__ __launch_bounds__(1024) void scan_kernel(const int* __restrict__ cnt,
                                                    int* __restrict__ rowptr) {
  __shared__ int part[1024];
  const int t = threadIdx.x;
  const int CHUNK = (N_NODES + 1023) / 1024;  // 98
  int base = t * CHUNK;
  int lim = min(base + CHUNK, N_NODES);
  int s = 0;
  for (int i = base; i < lim; ++i) s += cnt[i];
  part[t] = s;
  __syncthreads();
  for (int off = 1; off < 1024; off <<= 1) {
    int v = (t >= off) ? part[t - off] : 0;
    __syncthreads();
    part[t] += v;
    __syncthreads();
  }
  int excl = (t == 0) ? 0 : part[t - 1];
  for (int i = base; i < lim; ++i) { rowptr[i] = excl; excl += cnt[i]; }
  if (t == 1023) rowptr[N_NODES] = part[1023];
}

// ---------------------------------------------------------------- CSR scatter: {src, eid} sorted by dst
__global__ __launch_bounds__(256) void scatter_kernel(const int* __restrict__ ei,
                                                      const int* __restrict__ flags,
                                                      const int* __restrict__ rowptr,
                                                      int* __restrict__ fill,
                                                      int2* __restrict__ sev) {
  int e = blockIdx.x * 256 + threadIdx.x;
  if (e >= N_EDGES) return;
  int s, d;
  load_edge(ei, flags[0], e, s, d);
  int pos = atomicAdd(&fill[d], 1);
  sev[rowptr[d] + pos] = make_int2(s, e);
}

// ---------------------------------------------------------------- unified W pre-shuffle (1 launch)
// Groups 0..191 as R7 (upd K=256: 8x8; msg K=128: 8x4). Groups 192..207: W_e
// (msg rows 128..143) as K=32-PADDED frags for agg's edge-MFMA: 8 tiles per mat,
// b[j] = W[CH+k][t*16+col] if k<16 else 0.
__global__ __launch_bounds__(256) void wshuf_all(const void* __restrict__ wu1,
                                                 const void* __restrict__ wu2,
                                                 const void* __restrict__ wm1,
                                                 const void* __restrict__ wm2,
                                                 const int* __restrict__ flags,
                                                 ushort* __restrict__ ou1,
                                                 ushort* __restrict__ ou2,
                                                 ushort* __restrict__ om1,
                                                 ushort* __restrict__ om2,
                                                 ushort* __restrict__ oz1,
                                                 ushort* __restrict__ oz2) {
  const int MAP = flags[4], wf = flags[3];
  if (MAP == 2) return;
  int tid = blockIdx.x * 256 + threadIdx.x;  // 208 groups * 64 = 13312
  if (tid >= 13312) return;
  int gg = tid >> 6, lane = tid & 63;
  int col16 = lane & 15, g = lane >> 4;
  if (gg >= 192) {  // W_e frags
    int l = gg - 192;
    const void* W = (l < 8) ? wm1 : wm2;
    ushort* dst = (l < 8) ? oz1 : oz2;
    int t = l & 7;
#pragma unroll
    for (int j = 0; j < 8; ++j) {
      int k = kmap(MAP, g, j, 0);
      ushort v = (k < 16) ? f2bf(ldf(W, wf, (size_t)(CH + k) * CH + t * 16 + col16)) : (ushort)0;
      dst[(size_t)t * 512 + lane * 8 + j] = v;
    }
    return;
  }
  const void* W; ushort* dst; int t, step, ts;
  if (gg < 64)       { W = wu1; dst = ou1; int l = gg;       t = l >> 3; step = l & 7; ts = t * 8 + step; }
  else if (gg < 128) { W = wu2; dst = ou2; int l = gg - 64;  t = l >> 3; step = l & 7; ts = t * 8 + step; }
  else if (gg < 160) { W = wm1; dst = om1; int l = gg - 128; t = l >> 2; step = l & 3; ts = t * 4 + step; }
  else               { W = wm2; dst = om2; int l = gg - 160; t = l >> 2; step = l & 3; ts = t * 4 + step; }
  int col = t * 16 + col16;
#pragma unroll
  for (int j = 0; j < 8; ++j) {
    int k = kmap(MAP, g, j, step);
    dst[(size_t)ts * 512 + lane * 8 + j] = f2bf(ldf(W, wf, (size_t)k * CH + col));
  }
}

// ---------------------------------------------------------------- node GEMM y = x @ Wm[0:128] + b on MFMA (R7)
template <int MAP>
__device__ __forceinline__ void gemm_mfma_body(const void* __restrict__ x, int xf,
                                               const ushort* __restrict__ wshm,
                                               const void* __restrict__ bmsg, int wf,
                                               uint* __restrict__ ybf,
                                               int n0, int lane, char* lds) {
  const int srow = lane >> 2;
  const int q = lane & 3;
  {
    uint sw = (uint)((srow & 7) << 4);
#pragma unroll
    for (int i = 0; i < 8; ++i) {
      int qi = q + 4 * i;  // float4 index within 128-ch row
      float4 v = ld4(x, xf, (size_t)(n0 + srow) * 32 + qi);
      uint2 pk;
      pk.x = (uint)f2bf(v.x) | ((uint)f2bf(v.y) << 16);
      pk.y = (uint)f2bf(v.z) | ((uint)f2bf(v.w) << 16);
      *(uint2*)(lds + (((uint)srow * 256u + (uint)qi * 8u) ^ sw)) = pk;
    }
  }
  asm volatile("s_waitcnt lgkmcnt(0)" ::: "memory");
  __builtin_amdgcn_sched_barrier(0);

  const int col = lane & 15, g = lane >> 4;
  const int ra = lane & 15;
  const uint asw = (uint)((ra & 7) << 4);
  f32x4 acc[8];
#pragma unroll
  for (int t = 0; t < 8; ++t) acc[t] = (f32x4){0.f, 0.f, 0.f, 0.f};

#pragma unroll
  for (int step = 0; step < 4; ++step) {
    short8v a;
    if (MAP) {
      uint byte = (uint)ra * 256u + (uint)(step * 32 + 8 * g) * 2u;
      *(uint4*)&a = *(const uint4*)(lds + (byte ^ asw));
    } else {
      uint b0 = (uint)ra * 256u + (uint)(step * 32 + 4 * g) * 2u;
      uint b1 = b0 + 32u;
      uint2 lo = *(const uint2*)(lds + (b0 ^ asw));
      uint2 hi = *(const uint2*)(lds + (b1 ^ asw));
      uint4 pk = make_uint4(lo.x, lo.y, hi.x, hi.y);
      *(uint4*)&a = pk;
    }
#pragma unroll
    for (int t = 0; t < 8; ++t) {
      short8v b = *(const short8v*)(wshm + ((size_t)(t * 4 + step) * 512 + lane * 8));
      acc[t] = __builtin_amdgcn_mfma_f32_16x16x32_bf16(a, b, acc[t], 0, 0, 0);
    }
  }

#pragma unroll
  for (int u = 0; u < 4; ++u) {
    float b0v = ldf(bmsg, wf, u * 32 + col);        // ch of tile 2u  : 32u+col
    float b1v = ldf(bmsg, wf, u * 32 + 16 + col);   // ch of tile 2u+1: 32u+16+col
#pragma unroll
    for (int r = 0; r < 4; ++r) {
      uint pk = (uint)f2bf(acc[2 * u][r] + b0v) | ((uint)f2bf(acc[2 * u + 1][r] + b1v) << 16);
      ybf[(uint)(n0 + g * 4 + r) * 64u + (uint)(u * 16 + col)] = pk;
    }
  }
}

// f32 fallback: canonical ybf pairing (2*lane, 2*lane+1); 2 chunks of 8 rows.
__device__ __forceinline__ void gemm_f32_body(const void* __restrict__ x, int xf,
                                              const void* __restrict__ W, int wf,
                                              const void* __restrict__ b,
                                              uint* __restrict__ ybf,
                                              int wave_n0, int lane, char* ldsc) {
  float* xs = (float*)ldsc;  // [8][128] per-wave 4KB
  for (int c = 0; c < 2; ++c) {
    int n0 = wave_n0 + c * 8;
#pragma unroll
    for (int r = 0; r < NPW; ++r) {
      float2 a = ld2(x, xf, (size_t)(n0 + r) * 64 + lane);
      xs[r * 128 + 2 * lane]     = a.x;
      xs[r * 128 + 2 * lane + 1] = a.y;
    }
    asm volatile("s_waitcnt lgkmcnt(0)" ::: "memory");
    __builtin_amdgcn_sched_barrier(0);
    float acc0[NPW], acc1[NPW];
#pragma unroll
    for (int r = 0; r < NPW; ++r) { acc0[r] = 0.f; acc1[r] = 0.f; }
#pragma unroll 4
    for (int k = 0; k < CH; k += 2) {
      float2 w0 = ld2(W, wf, (size_t)k * 64 + lane);
      float2 w1 = ld2(W, wf, (size_t)(k + 1) * 64 + lane);
#pragma unroll
      for (int r = 0; r < NPW; ++r) {
        float2 a = *(const float2*)&xs[r * 128 + k];
        acc0[r] += a.x * w0.x;
        acc1[r] += a.x * w0.y;
        acc0[r] += a.y * w1.x;
        acc1[r] += a.y * w1.y;
      }
    }
    float2 bb = ld2(b, wf, lane);
#pragma unroll
    for (int r = 0; r < NPW; ++r) {
      uint pk = (uint)f2bf(acc0[r] + bb.x) | ((uint)f2bf(acc1[r] + bb.y) << 16);
      ybf[(uint)(n0 + r) * 64u + (uint)lane] = pk;
    }
  }
}

__global__ __launch_bounds__(256) void gemm_node(const void* __restrict__ x, int x_sel,
                                                 const ushort* __restrict__ wshm,
                                                 const void* __restrict__ W,
                                                 const void* __restrict__ b,
                                                 const int* __restrict__ flags,
                                                 uint* __restrict__ ybf) {
  __shared__ char lds[16384];  // 4 KB per wave
  const int wave = threadIdx.x >> 6;
  const int lane = threadIdx.x & 63;
  const int wid = blockIdx.x * 4 + wave;
  if (wid >= N_NODES / 16) return;
  const int n0 = wid * 16;
  const int xf = resolve_f32(x_sel, flags), wf = flags[3];
  const int MAP = flags[4];
  char* myl = lds + wave * 4096;
  if (MAP == 0)      gemm_mfma_body<0>(x, xf, wshm, b, wf, ybf, n0, lane, myl);
  else if (MAP == 1) gemm_mfma_body<1>(x, xf, wshm, b, wf, ybf, n0, lane, myl);
  else               gemm_f32_body(x, xf, W, wf, b, ybf, n0, lane, myl);
}

// ---------------------------------------------------------------- CSR aggregation with edge-MFMA:
// One wave per dst node, 16-edge MFMA batches. A = ea rows (16 edges x K=32,
// dims>=16 zero); B = K=32-padded W_e frags (held in 32 VGPRs). The Z fragment
// C-layout (row = edge slot g*4+r, col = t*16+col) aligns with ybf's frag-pair
// slots: uint y[s][u*16+col] = channels of tiles (2u, 2u+1) = zf[2u]/zf[2u+1]
// in the SAME lane. Epilogue: 16 gathers + ~8 VALU/edge (vs ~130 in the scalar
// R7 body). Tail edges masked by validity multiplier; f32 accumulate throughout.
template <int MAP>
__device__ __forceinline__ void agg_mfma_body(const uint* __restrict__ ybf,
                                              const void* __restrict__ ea, int ef,
                                              const ushort* __restrict__ wze,
                                              const int* __restrict__ rowptr,
                                              const int2* __restrict__ sev,
                                              float* __restrict__ agg,
                                              int n, int lane) {
  const int col = lane & 15, g = lane >> 4;
  const int beg = rowptr[n], end = rowptr[n + 1];
  if (beg == end) {  // zero-degree: mean of empty set = 0
    agg[(size_t)n * CH + (size_t)(2 * g) * 16 + col]     = 0.f;
    agg[(size_t)n * CH + (size_t)(2 * g + 1) * 16 + col] = 0.f;
    return;
  }
  short8v bfr[8];
#pragma unroll
  for (int t = 0; t < 8; ++t)
    bfr[t] = *(const short8v*)(wze + ((size_t)t * 512 + lane * 8));

  f32x4 acc[8];
#pragma unroll
  for (int t = 0; t < 8; ++t) acc[t] = (f32x4){0.f, 0.f, 0.f, 0.f};

  for (int j0 = beg; j0 < end; j0 += 16) {
    int jr = j0 + col;              // this lane stages A-row 'col'
    if (jr > end - 1) jr = end - 1;
    int2 p = sev[jr];
    int e = p.y;
    short8v a;
    if (MAP == 1) {                 // k = 8g+j: dims 8g..8g+7 (g<2), zero g>=2
      if (g < 2) {
        float4 qa = ld4(ea, ef, (size_t)e * 4 + 2 * g);
        float4 qb = ld4(ea, ef, (size_t)e * 4 + 2 * g + 1);
        uint4 pk;
        pk.x = (uint)f2bf(qa.x) | ((uint)f2bf(qa.y) << 16);
        pk.y = (uint)f2bf(qa.z) | ((uint)f2bf(qa.w) << 16);
        pk.z = (uint)f2bf(qb.x) | ((uint)f2bf(qb.y) << 16);
        pk.w = (uint)f2bf(qb.z) | ((uint)f2bf(qb.w) << 16);
        *(uint4*)&a = pk;
      } else {
        *(uint4*)&a = make_uint4(0, 0, 0, 0);
      }
    } else {                        // MAP0: j<4 -> k=4g+j (real); j>=4 -> k>=16 zero
      float4 q = ld4(ea, ef, (size_t)e * 4 + g);
      uint4 pk;
      pk.x = (uint)f2bf(q.x) | ((uint)f2bf(q.y) << 16);
      pk.y = (uint)f2bf(q.z) | ((uint)f2bf(q.w) << 16);
      pk.z = 0; pk.w = 0;
      *(uint4*)&a = pk;
    }
    f32x4 zz = {0.f, 0.f, 0.f, 0.f};
    f32x4 zf[8];
#pragma unroll
    for (int t = 0; t < 8; ++t)
      zf[t] = __builtin_amdgcn_mfma_f32_16x16x32_bf16(a, bfr[t], zz, 0, 0, 0);

    int myS = p.x;                  // src of edge slot 'col' (lanes 0..15 authoritative)
#pragma unroll
    for (int r = 0; r < 4; ++r) {
      int slot = g * 4 + r;
      int s = __shfl(myS, slot);    // lane 'slot' holds sev[j0+slot]
      float valid = (j0 + slot < end) ? 1.f : 0.f;
#pragma unroll
      for (int u = 0; u < 4; ++u) {
        uint yu = ybf[(size_t)s * 64 + (size_t)u * 16 + col];
        float lo = bf2f((ushort)(yu & 0xFFFF));
        float hi = bf2f((ushort)(yu >> 16));
        acc[2 * u][r]     += valid * fmaxf(lo + zf[2 * u][r], 0.f);
        acc[2 * u + 1][r] += valid * fmaxf(hi + zf[2 * u + 1][r], 0.f);
      }
    }
  }
  float part[8];
#pragma unroll
  for (int t = 0; t < 8; ++t) {
    part[t] = (acc[t][0] + acc[t][1]) + (acc[t][2] + acc[t][3]);
    part[t] += __shfl_xor(part[t], 16);
    part[t] += __shfl_xor(part[t], 32);  // all g-replicas now hold full sums
  }
  agg[(size_t)n * CH + (size_t)(2 * g) * 16 + col]     = part[2 * g];
  agg[(size_t)n * CH + (size_t)(2 * g + 1) * 16 + col] = part[2 * g + 1];
}

// Scalar fallback (MAP==2): R7 body, canonical channel pairing.
__device__ __forceinline__ void agg_f32_body(const uint* __restrict__ ybf,
                                             const void* __restrict__ ea, int ef,
                                             const void* __restrict__ W, int wf,
                                             const int* __restrict__ rowptr,
                                             const int2* __restrict__ sev,
                                             float* __restrict__ agg,
                                             int n, int lane) {
  const int c0 = 2 * lane, c1 = c0 + 1;
  float wex[EDGE_DIM], wey[EDGE_DIM];
#pragma unroll
  for (int k = 0; k < EDGE_DIM; ++k) {
    wex[k] = ldf(W, wf, (size_t)(CH + k) * CH + c0);
    wey[k] = ldf(W, wf, (size_t)(CH + k) * CH + c1);
  }
  const int beg = rowptr[n], end = rowptr[n + 1];
  float acc0 = 0.f, acc1 = 0.f;
  for (int j = beg; j < end; ++j) {
    int2 p = sev[j];
    int s = __builtin_amdgcn_readfirstlane(p.x), e = __builtin_amdgcn_readfirstlane(p.y);
    uint yu = ybf[(size_t)s * 64 + lane];
    float4 q0 = ld4(ea, ef, (size_t)e * 4 + 0);
    float4 q1 = ld4(ea, ef, (size_t)e * 4 + 1);
    float4 q2 = ld4(ea, ef, (size_t)e * 4 + 2);
    float4 q3 = ld4(ea, ef, (size_t)e * 4 + 3);
    float av[16] = {q0.x, q0.y, q0.z, q0.w, q1.x, q1.y, q1.z, q1.w,
                    q2.x, q2.y, q2.z, q2.w, q3.x, q3.y, q3.z, q3.w};
    float z0 = 0.f, z1 = 0.f;
#pragma unroll
    for (int k = 0; k < EDGE_DIM; ++k) {
      z0 += av[k] * wex[k];
      z1 += av[k] * wey[k];
    }
    acc0 += fmaxf(bf2f((ushort)(yu & 0xFFFF)) + z0, 0.f);
    acc1 += fmaxf(bf2f((ushort)(yu >> 16)) + z1, 0.f);
  }
  agg[(size_t)n * CH + c0] = acc0;
  agg[(size_t)n * CH + c1] = acc1;
}

__global__ __launch_bounds__(256) void agg_csr(const uint* __restrict__ ybf,
                                               const void* __restrict__ ea,
                                               const ushort* __restrict__ wze,
                                               const void* __restrict__ W,
                                               const int* __restrict__ rowptr,
                                               const int2* __restrict__ sev,
                                               const int* __restrict__ flags,
                                               float* __restrict__ agg) {
  const int wave = threadIdx.x >> 6;
  const int lane = threadIdx.x & 63;
  const int n = blockIdx.x * 4 + wave;  // grid = N/4 exactly
  const int ef = flags[2], wf = flags[3], MAP = flags[4];
  if (MAP == 0)      agg_mfma_body<0>(ybf, ea, ef, wze, rowptr, sev, agg, n, lane);
  else if (MAP == 1) agg_mfma_body<1>(ybf, ea, ef, wze, rowptr, sev, agg, n, lane);
  else               agg_f32_body(ybf, ea, ef, W, wf, rowptr, sev, agg, n, lane);
}

// ---------------------------------------------------------------- update GEMM on MFMA + fused norm (R6, unchanged)
template <int MAP>
__device__ __forceinline__ void upd_mfma_body(const void* __restrict__ x, int xf,
                                              const float* __restrict__ agg,
                                              const int* __restrict__ rowptr,
                                              const ushort* __restrict__ wsh,
                                              const void* __restrict__ bupd, int wf,
                                              const void* __restrict__ bias,
                                              float* __restrict__ out, int relu,
                                              int n0, int lane, char* lds) {
  const int srow = lane >> 2;
  const int q = lane & 3;
  {
    int c = rowptr[n0 + srow + 1] - rowptr[n0 + srow];
    float inv = 1.f / (float)(c > 1 ? c : 1);
    uint sw = (uint)((srow & 7) << 4);
#pragma unroll
    for (int i = 0; i < 8; ++i) {
      int qi = q + 4 * i;
      float4 v = ld4(x, xf, (size_t)(n0 + srow) * 32 + qi);
      uint2 pk;
      pk.x = (uint)f2bf(v.x) | ((uint)f2bf(v.y) << 16);
      pk.y = (uint)f2bf(v.z) | ((uint)f2bf(v.w) << 16);
      *(uint2*)(lds + (((uint)srow * 512u + (uint)qi * 8u) ^ sw)) = pk;
      float4 w = ((const float4*)agg)[(size_t)(n0 + srow) * 32 + qi];
      uint2 pk2;
      pk2.x = (uint)f2bf(w.x * inv) | ((uint)f2bf(w.y * inv) << 16);
      pk2.y = (uint)f2bf(w.z * inv) | ((uint)f2bf(w.w * inv) << 16);
      *(uint2*)(lds + (((uint)srow * 512u + 256u + (uint)qi * 8u) ^ sw)) = pk2;
    }
  }
  asm volatile("s_waitcnt lgkmcnt(0)" ::: "memory");
  __builtin_amdgcn_sched_barrier(0);

  const int col = lane & 15, g = lane >> 4;
  const int ra = lane & 15;
  const uint asw = (uint)((ra & 7) << 4);
  f32x4 acc[8];
#pragma unroll
  for (int t = 0; t < 8; ++t) acc[t] = (f32x4){0.f, 0.f, 0.f, 0.f};

#pragma unroll
  for (int step = 0; step < 8; ++step) {
    short8v a;
    if (MAP) {
      uint byte = (uint)ra * 512u + (uint)(step * 32 + 8 * g) * 2u;
      *(uint4*)&a = *(const uint4*)(lds + (byte ^ asw));
    } else {
      uint b0 = (uint)ra * 512u + (uint)(step * 32 + 4 * g) * 2u;
      uint b1 = b0 + 32u;
      uint2 lo = *(const uint2*)(lds + (b0 ^ asw));
      uint2 hi = *(const uint2*)(lds + (b1 ^ asw));
      uint4 pk = make_uint4(lo.x, lo.y, hi.x, hi.y);
      *(uint4*)&a = pk;
    }
#pragma unroll
    for (int t = 0; t < 8; ++t) {
      short8v b = *(const short8v*)(wsh + ((size_t)(t * 8 + step) * 512 + lane * 8));
      acc[t] = __builtin_amdgcn_mfma_f32_16x16x32_bf16(a, b, acc[t], 0, 0, 0);
    }
  }

  float bu[8], bi[8];
#pragma unroll
  for (int t = 0; t < 8; ++t) {
    bu[t] = ldf(bupd, wf, t * 16 + col);
    bi[t] = ldf(bias, wf, t * 16 + col);
  }
  float raw[8][4];
  float ss[4] = {0.f, 0.f, 0.f, 0.f};
#pragma unroll
  for (int t = 0; t < 8; ++t)
#pragma unroll
    for (int r = 0; r < 4; ++r) {
      float v = acc[t][r] + bu[t];
      raw[t][r] = v;
      ss[r] += v * v;
    }
#pragma unroll
  for (int r = 0; r < 4; ++r)
#pragma unroll
    for (int o = 1; o < 16; o <<= 1) ss[r] += __shfl_xor(ss[r], o);
#pragma unroll
  for (int r = 0; r < 4; ++r) {
    float inv = 1.0f / fmaxf(sqrtf(ss[r]), 1e-12f);
    int row = g * 4 + r;
#pragma unroll
    for (int t = 0; t < 8; ++t) {
      float o = raw[t][r] * inv + bi[t];
      if (relu) o = fmaxf(o, 0.f);
      out[(size_t)(n0 + row) * CH + t * 16 + col] = o;
    }
  }
}

__device__ __forceinline__ void upd_f32_body(const void* __restrict__ x, int xf,
                                             const float* __restrict__ agg,
                                             const int* __restrict__ rowptr,
                                             const void* __restrict__ W, int wf,
                                             const void* __restrict__ bupd,
                                             const void* __restrict__ bias,
                                             float* __restrict__ out, int relu,
                                             int wave_n0, int lane, char* ldsc) {
  float* xs = (float*)ldsc;  // [8][256] f32 = 8 KB per-wave slice
  for (int c = 0; c < 2; ++c) {
    int n0 = wave_n0 + c * 8;
#pragma unroll
    for (int r = 0; r < NPW; ++r) {
      int n = n0 + r;
      float2 a = ld2(x, xf, (size_t)n * 64 + lane);
      xs[r * 256 + 2 * lane]     = a.x;
      xs[r * 256 + 2 * lane + 1] = a.y;
      int cd = rowptr[n + 1] - rowptr[n];
      float inv = 1.f / (float)(cd > 1 ? cd : 1);
      xs[r * 256 + CH + 2 * lane]     = agg[(size_t)n * CH + 2 * lane] * inv;
      xs[r * 256 + CH + 2 * lane + 1] = agg[(size_t)n * CH + 2 * lane + 1] * inv;
    }
    asm volatile("s_waitcnt lgkmcnt(0)" ::: "memory");
    __builtin_amdgcn_sched_barrier(0);

    float acc0[NPW], acc1[NPW];
#pragma unroll
    for (int r = 0; r < NPW; ++r) { acc0[r] = 0.f; acc1[r] = 0.f; }
#pragma unroll 4
    for (int k = 0; k < KUPD; k += 2) {
      float2 w0 = ld2(W, wf, (size_t)k * 64 + lane);
      float2 w1 = ld2(W, wf, (size_t)(k + 1) * 64 + lane);
#pragma unroll
      for (int r = 0; r < NPW; ++r) {
        float2 a = *(const float2*)&xs[r * 256 + k];
        acc0[r] += a.x * w0.x;
        acc1[r] += a.x * w0.y;
        acc0[r] += a.y * w1.x;
        acc1[r] += a.y * w1.y;
      }
    }
    float2 b  = ld2(bupd, wf, lane);
    float2 bi = ld2(bias, wf, lane);
#pragma unroll
    for (int r = 0; r < NPW; ++r) {
      float r0 = acc0[r] + b.x;
      float r1 = acc1[r] + b.y;
      float sq = r0 * r0 + r1 * r1;
#pragma unroll
      for (int o = 32; o; o >>= 1) sq += __shfl_xor(sq, o);
      float innv = 1.0f / fmaxf(sqrtf(sq), 1e-12f);
      float o0 = r0 * innv + bi.x;
      float o1 = r1 * innv + bi.y;
      if (relu) { o0 = fmaxf(o0, 0.f); o1 = fmaxf(o1, 0.f); }
      size_t n = (size_t)(n0 + r);
      out[n * CH + 2 * lane]     = o0;
      out[n * CH + 2 * lane + 1] = o1;
    }
  }
}

__global__ __launch_bounds__(256) void upd_fused(const void* __restrict__ x, int x_sel,
                                                 const float* __restrict__ agg,
                                                 const int* __restrict__ rowptr,
                                                 const ushort* __restrict__ wsh,
                                                 const void* __restrict__ W,
                                                 const void* __restrict__ bupd,
                                                 const void* __restrict__ bias,
                                                 const int* __restrict__ flags,
                                                 float* __restrict__ out,
                                                 int relu) {
  __shared__ char lds[32768];  // 8 KB per wave
  const int wave = threadIdx.x >> 6;
  const int lane = threadIdx.x & 63;
  const int wid = blockIdx.x * 4 + wave;
  if (wid >= N_NODES / 16) return;
  const int n0 = wid * 16;
  const int xf = resolve_f32(x_sel, flags), wf = flags[3];
  const int MAP = flags[4];
  char* myl = lds + wave * 8192;
  if (MAP == 0)
    upd_mfma_body<0>(x, xf, agg, rowptr, wsh, bupd, wf, bias, out, relu, n0, lane, myl);
  else if (MAP == 1)
    upd_mfma_body<1>(x, xf, agg, rowptr, wsh, bupd, wf, bias, out, relu, n0, lane, myl);
  else
    upd_f32_body(x, xf, agg, rowptr, W, wf, bupd, bias, out, relu, n0, lane, myl);
}

// ---------------------------------------------------------------- host
extern "C" void kernel_launch(void* const* d_in, const int* in_sizes, int n_in,
                              void* d_out, int out_size, void* d_ws, size_t ws_size,
                              hipStream_t stream) {
  const void* x   = d_in[0];
  const int*  ei  = (const int*)d_in[1];
  const void* ea  = d_in[2];
  const void* wm1 = d_in[3];
  const void* bm1 = d_in[4];
  const void* wu1 = d_in[5];
  const void* bu1 = d_in[6];
  const void* bi1 = d_in[7];
  const void* wm2 = d_in[8];
  const void* bm2 = d_in[9];
  const void* wu2 = d_in[10];
  const void* bu2 = d_in[11];
  const void* bi2 = d_in[12];
  float* out = (float*)d_out;

  char* base = (char*)d_ws;
  size_t off = 0;
  auto alloc = [&](size_t b) { size_t o = off; off += (b + 255) & ~(size_t)255; return o; };
  size_t flags_o = alloc(32);
  size_t cnt_o   = alloc((size_t)N_NODES * 4);
  size_t fill_o  = alloc((size_t)N_NODES * 4);
  size_t zero_end = off;                       // memset covers flags|cnt|fill only
  size_t rowp_o  = alloc((size_t)(N_NODES + 1) * 4);
  size_t sev_o   = alloc((size_t)N_EDGES * 8);
  size_t agg_o   = alloc((size_t)N_NODES * CH * 4);
  size_t y_o     = alloc((size_t)N_NODES * CH * 2);   // packed bf16
  size_t wsh1_o  = alloc((size_t)4096 * 8 * 2);       // upd W1 frags, 64 KB
  size_t wsh2_o  = alloc((size_t)4096 * 8 * 2);       // upd W2 frags
  size_t wshm1_o = alloc((size_t)2048 * 8 * 2);       // msg W1[0:128] frags, 32 KB
  size_t wshm2_o = alloc((size_t)2048 * 8 * 2);       // msg W2[0:128] frags
  size_t wze1_o  = alloc((size_t)512 * 8 * 2);        // W_e1 K=32-padded frags, 8 KB
  size_t wze2_o  = alloc((size_t)512 * 8 * 2);        // W_e2
  (void)ws_size; (void)n_in; (void)in_sizes; (void)out_size;

  int*    flags = (int*)(base + flags_o);
  int*    cntp  = (int*)(base + cnt_o);
  int*    fillp = (int*)(base + fill_o);
  int*    rowp  = (int*)(base + rowp_o);
  int2*   sevp  = (int2*)(base + sev_o);
  float*  aggp  = (float*)(base + agg_o);
  uint*   ybfp  = (uint*)(base + y_o);
  ushort* wsh1  = (ushort*)(base + wsh1_o);
  ushort* wsh2  = (ushort*)(base + wsh2_o);
  ushort* wshm1 = (ushort*)(base + wshm1_o);
  ushort* wshm2 = (ushort*)(base + wshm2_o);
  ushort* wze1  = (ushort*)(base + wze1_o);
  ushort* wze2  = (ushort*)(base + wze2_o);
  float*  hp    = out;                  // layer-1 output (f32) lives in d_out

  hipMemsetAsync(base, 0, zero_end, stream);
  detect_kernel<<<1, 256, 0, stream>>>(ei, (const ushort*)x, (const ushort*)ea,
                                       (const ushort*)wm1, flags);
  mfma_probe<<<1, 64, 0, stream>>>(flags);
  count_kernel<<<(N_EDGES + 255) / 256, 256, 0, stream>>>(ei, flags, cntp);
  scan_kernel<<<1, 1024, 0, stream>>>(cntp, rowp);
  scatter_kernel<<<(N_EDGES + 255) / 256, 256, 0, stream>>>(ei, flags, rowp, fillp, sevp);
  wshuf_all<<<52, 256, 0, stream>>>(wu1, wu2, wm1, wm2, flags,
                                    wsh1, wsh2, wshm1, wshm2, wze1, wze2);

  const int agrid = N_NODES / 4;             // 25000
  const int wgrid = (N_NODES / 16 + 3) / 4;  // 1563 (4 waves x 16 rows)

  // ---- layer 1
  gemm_node<<<wgrid, 256, 0, stream>>>(x, 1, wshm1, wm1, bm1, flags, ybfp);
  agg_csr<<<agrid, 256, 0, stream>>>(ybfp, ea, wze1, wm1, rowp, sevp, flags, aggp);
  upd_fused<<<wgrid, 256, 0, stream>>>(x, 1, aggp, rowp, wsh1, wu1, bu1, bi1, flags, hp, 1);

  // ---- layer 2 (h is f32 in d_out -> x_sel=2 forces f32)
  gemm_node<<<wgrid, 256, 0, stream>>>(hp, 2, wshm2, wm2, bm2, flags, ybfp);
  agg_csr<<<agrid, 256, 0, stream>>>(ybfp, ea, wze2, wm2, rowp, sevp, flags, aggp);
  upd_fused<<<wgrid, 256, 0, stream>>>(hp, 2, aggp, rowp, wsh2, wu2, bu2, bi2, flags, out, 0);
}

// Round 10
// 968.465 us; speedup vs baseline: 1.4564x; 1.0397x over previous
//
#include <hip/hip_runtime.h>
#include <stdint.h>

#define N_NODES 100000
#define N_EDGES 1600000
#define CH 128
#define EDGE_DIM 16
#define KUPD 256
#define NPW 8

typedef __attribute__((ext_vector_type(8))) short short8v;   // 8 bf16 (4 VGPRs)
typedef __attribute__((ext_vector_type(4))) float f32x4;

__device__ __forceinline__ float bf2f(ushort u) {
  union { uint i; float f; } c; c.i = ((uint)u) << 16; return c.f;
}
__device__ __forceinline__ ushort f2bf(float f) {
  union { float f; uint i; } c; c.f = f;
  return (ushort)((c.i + 0x7FFFu + ((c.i >> 16) & 1u)) >> 16);
}
__device__ __forceinline__ float ldf(const void* p, int f32, size_t i) {
  return f32 ? ((const float*)p)[i] : bf2f(((const ushort*)p)[i]);
}
__device__ __forceinline__ float2 ld2(const void* p, int f32, size_t pi) {
  if (f32) return ((const float2*)p)[pi];
  uint u = ((const uint*)p)[pi];
  return make_float2(bf2f((ushort)(u & 0xFFFF)), bf2f((ushort)(u >> 16)));
}
__device__ __forceinline__ float4 ld4(const void* p, int f32, size_t qi) {
  if (f32) return ((const float4*)p)[qi];
  uint2 u = ((const uint2*)p)[qi];
  float4 r;
  r.x = bf2f((ushort)(u.x & 0xFFFF)); r.y = bf2f((ushort)(u.x >> 16));
  r.z = bf2f((ushort)(u.y & 0xFFFF)); r.w = bf2f((ushort)(u.y >> 16));
  return r;
}
// x_sel: 0 = force bf16, 1 = use detected x flag, 2 = force f32
__device__ __forceinline__ int resolve_f32(int x_sel, const int* flags) {
  return (x_sel == 2) ? 1 : (x_sel == 1 ? flags[1] : 0);
}
// MFMA A/B k-mapping candidates. g = lane>>4, j = frag element 0..7.
// MAP0 (interleaved), MAP1 (contiguous). Verified at runtime by the probe.
__device__ __forceinline__ int kmap(int MAP, int g, int j, int step) {
  return MAP ? (step * 32 + 8 * g + j)
             : (step * 32 + 16 * (j >> 2) + 4 * g + (j & 3));
}

// ---------------------------------------------------------------- detection + MFMA probe (merged, 1 dispatch)
// flags[0]=1 -> edge_index int32 [2,E]. flags[1..3]=1 -> x / edge_attr / weights f32.
// flags[4] = MFMA k-mapping (0/1) or 2 = no candidate verified -> f32 fallback.
__global__ __launch_bounds__(256) void detect_probe(const int* __restrict__ ei,
                                                    const ushort* __restrict__ xu,
                                                    const ushort* __restrict__ eau,
                                                    const ushort* __restrict__ wu,
                                                    int* __restrict__ flags) {
  __shared__ ushort A[16 * 32];
  __shared__ ushort B[32 * 16];
  // dtype/layout detection (all 256 threads)
  int any = 0, fx = 0, fe = 0, fw = 0;
  for (int i = threadIdx.x; i < 4096; i += 256) any |= ei[2 * i + 1];
  for (int i = threadIdx.x; i < 16384; i += 256) {
    fx |= (((xu[2 * i] >> 7) & 0xFF) == 0xFF);
    fe |= (((eau[2 * i] >> 7) & 0xFF) == 0xFF);
  }
  for (int i = threadIdx.x; i < 8192; i += 256) {
    fw |= (((wu[2 * i] >> 7) & 0xFF) == 0xFF);
  }
  if (any) atomicOr(flags + 0, 1);
  if (fx)  atomicOr(flags + 1, 1);
  if (fe)  atomicOr(flags + 2, 1);
  if (fw)  atomicOr(flags + 3, 1);
  // fill probe matrices (all 256 threads), then wave 0 runs the MFMA probe
  for (int idx = threadIdx.x; idx < 512; idx += 256) {
    int i = idx >> 5, k = idx & 31;
    A[idx] = f2bf((float)((i * 5 + k * 3) % 13 - 6));
    int k2 = idx >> 4, c = idx & 15;
    B[idx] = f2bf((float)((k2 * 7 + c * 11) % 15 - 7));
  }
  __syncthreads();
  if (threadIdx.x < 64) {
    const int lane = threadIdx.x;
    const int col = lane & 15, g = lane >> 4;
    float cr[4];
#pragma unroll
    for (int r = 0; r < 4; ++r) {
      int row = g * 4 + r;
      float s = 0.f;
      for (int k = 0; k < 32; ++k) s += bf2f(A[row * 32 + k]) * bf2f(B[k * 16 + col]);
      cr[r] = s;
    }
    int win = 2;
    for (int MAP = 0; MAP < 2; ++MAP) {
      if (win != 2) break;
      short8v a, b;
#pragma unroll
      for (int j = 0; j < 8; ++j) {
        int k = kmap(MAP, g, j, 0);
        a[j] = (short)A[(lane & 15) * 32 + k];
        b[j] = (short)B[k * 16 + col];
      }
      f32x4 z = {0.f, 0.f, 0.f, 0.f};
      f32x4 d = __builtin_amdgcn_mfma_f32_16x16x32_bf16(a, b, z, 0, 0, 0);
      int good = 1;
#pragma unroll
      for (int r = 0; r < 4; ++r) good &= (d[r] == cr[r]);
      if (__all(good)) win = MAP;
    }
    if (lane == 0) flags[4] = win;
  }
}

__device__ __forceinline__ void load_edge(const int* __restrict__ ei, int i32, int e,
                                          int& s, int& d) {
  if (i32) { s = ei[e]; d = ei[N_EDGES + e]; }
  else     { s = ei[2 * e]; d = ei[2 * N_EDGES + 2 * e]; }
  s = min(max(s, 0), N_NODES - 1);
  d = min(max(d, 0), N_NODES - 1);
}

// ---------------------------------------------------------------- degree count (dst only)
__global__ __launch_bounds__(256) void count_kernel(const int* __restrict__ ei,
                                                    const int* __restrict__ flags,
                                                    int* __restrict__ cnt) {
  int e = blockIdx.x * 256 + threadIdx.x;
  if (e >= N_EDGES) return;
  int d = flags[0] ? ei[N_EDGES + e] : ei[2 * N_EDGES + 2 * e];
  d = min(max(d, 0), N_NODES - 1);
  atomicAdd(&cnt[d], 1);
}

// ---------------------------------------------------------------- exclusive prefix scan of cnt -> rowptr
__global__ __launch_bounds__(1024) void scan_kernel(const int* __restrict__ cnt,
                                                    int* __restrict__ rowptr) {
  __shared__ int part[1024];
  const int t = threadIdx.x;
  const int CHUNK = (N_NODES + 1023) / 1024;  // 98
  int base = t * CHUNK;
  int lim = min(base + CHUNK, N_NODES);
  int s = 0;
  for (int i = base; i < lim; ++i) s += cnt[i];
  part[t] = s;
  __syncthreads();
  for (int off = 1; off < 1024; off <<= 1) {
    int v = (t >= off) ? part[t - off] : 0;
    __syncthreads();
    part[t] += v;
    __syncthreads();
  }
  int excl = (t == 0) ? 0 : part[t - 1];
  for (int i = base; i < lim; ++i) { rowptr[i] = excl; excl += cnt[i]; }
  if (t == 1023) rowptr[N_NODES] = part[1023];
}

// ---------------------------------------------------------------- CSR scatter: {src, eid} sorted by dst
__global__ __launch_bounds__(256) void scatter_kernel(const int* __restrict__ ei,
                                                      const int* __restrict__ flags,
                                                      const int* __restrict__ rowptr,
                                                      int* __restrict__ fill,
                                                      int2* __restrict__ sev) {
  int e = blockIdx.x * 256 + threadIdx.x;
  if (e >= N_EDGES) return;
  int s, d;
  load_edge(ei, flags[0], e, s, d);
  int pos = atomicAdd(&fill[d], 1);
  sev[rowptr[d] + pos] = make_int2(s, e);
}

// ---------------------------------------------------------------- unified W pre-shuffle (1 launch)
// Groups 0..191: upd K=256 (8x8) + msg K=128 (8x4). Groups 192..207: W_e rows
// 128..143 as K=32-PADDED frags. Group 208: zero ybf row N_NODES (tail-mask row).
__global__ __launch_bounds__(256) void wshuf_all(const void* __restrict__ wu1,
                                                 const void* __restrict__ wu2,
                                                 const void* __restrict__ wm1,
                                                 const void* __restrict__ wm2,
                                                 const int* __restrict__ flags,
                                                 ushort* __restrict__ ou1,
                                                 ushort* __restrict__ ou2,
                                                 ushort* __restrict__ om1,
                                                 ushort* __restrict__ om2,
                                                 ushort* __restrict__ oz1,
                                                 ushort* __restrict__ oz2,
                                                 uint* __restrict__ ybf) {
  const int MAP = flags[4], wf = flags[3];
  if (MAP == 2) return;
  int tid = blockIdx.x * 256 + threadIdx.x;  // 209 groups * 64 = 13376
  if (tid >= 13376) return;
  int gg = tid >> 6, lane = tid & 63;
  int col16 = lane & 15, g = lane >> 4;
  if (gg == 208) {  // zero row for tail masking in agg
    ybf[(size_t)N_NODES * 64 + lane] = 0u;
    return;
  }
  if (gg >= 192) {  // W_e frags
    int l = gg - 192;
    const void* W = (l < 8) ? wm1 : wm2;
    ushort* dst = (l < 8) ? oz1 : oz2;
    int t = l & 7;
#pragma unroll
    for (int j = 0; j < 8; ++j) {
      int k = kmap(MAP, g, j, 0);
      ushort v = (k < 16) ? f2bf(ldf(W, wf, (size_t)(CH + k) * CH + t * 16 + col16)) : (ushort)0;
      dst[(size_t)t * 512 + lane * 8 + j] = v;
    }
    return;
  }
  const void* W; ushort* dst; int t, step, ts;
  if (gg < 64)       { W = wu1; dst = ou1; int l = gg;       t = l >> 3; step = l & 7; ts = t * 8 + step; }
  else if (gg < 128) { W = wu2; dst = ou2; int l = gg - 64;  t = l >> 3; step = l & 7; ts = t * 8 + step; }
  else if (gg < 160) { W = wm1; dst = om1; int l = gg - 128; t = l >> 2; step = l & 3; ts = t * 4 + step; }
  else               { W = wm2; dst = om2; int l = gg - 160; t = l >> 2; step = l & 3; ts = t * 4 + step; }
  int col = t * 16 + col16;
#pragma unroll
  for (int j = 0; j < 8; ++j) {
    int k = kmap(MAP, g, j, step);
    dst[(size_t)ts * 512 + lane * 8 + j] = f2bf(ldf(W, wf, (size_t)k * CH + col));
  }
}

// ---------------------------------------------------------------- node GEMM y = x @ Wm[0:128] + b on MFMA (R7)
template <int MAP>
__device__ __forceinline__ void gemm_mfma_body(const void* __restrict__ x, int xf,
                                               const ushort* __restrict__ wshm,
                                               const void* __restrict__ bmsg, int wf,
                                               uint* __restrict__ ybf,
                                               int n0, int lane, char* lds) {
  const int srow = lane >> 2;
  const int q = lane & 3;
  {
    uint sw = (uint)((srow & 7) << 4);
#pragma unroll
    for (int i = 0; i < 8; ++i) {
      int qi = q + 4 * i;  // float4 index within 128-ch row
      float4 v = ld4(x, xf, (size_t)(n0 + srow) * 32 + qi);
      uint2 pk;
      pk.x = (uint)f2bf(v.x) | ((uint)f2bf(v.y) << 16);
      pk.y = (uint)f2bf(v.z) | ((uint)f2bf(v.w) << 16);
      *(uint2*)(lds + (((uint)srow * 256u + (uint)qi * 8u) ^ sw)) = pk;
    }
  }
  asm volatile("s_waitcnt lgkmcnt(0)" ::: "memory");
  __builtin_amdgcn_sched_barrier(0);

  const int col = lane & 15, g = lane >> 4;
  const int ra = lane & 15;
  const uint asw = (uint)((ra & 7) << 4);
  f32x4 acc[8];
#pragma unroll
  for (int t = 0; t < 8; ++t) acc[t] = (f32x4){0.f, 0.f, 0.f, 0.f};

#pragma unroll
  for (int step = 0; step < 4; ++step) {
    short8v a;
    if (MAP) {
      uint byte = (uint)ra * 256u + (uint)(step * 32 + 8 * g) * 2u;
      *(uint4*)&a = *(const uint4*)(lds + (byte ^ asw));
    } else {
      uint b0 = (uint)ra * 256u + (uint)(step * 32 + 4 * g) * 2u;
      uint b1 = b0 + 32u;
      uint2 lo = *(const uint2*)(lds + (b0 ^ asw));
      uint2 hi = *(const uint2*)(lds + (b1 ^ asw));
      uint4 pk = make_uint4(lo.x, lo.y, hi.x, hi.y);
      *(uint4*)&a = pk;
    }
#pragma unroll
    for (int t = 0; t < 8; ++t) {
      short8v b = *(const short8v*)(wshm + ((size_t)(t * 4 + step) * 512 + lane * 8));
      acc[t] = __builtin_amdgcn_mfma_f32_16x16x32_bf16(a, b, acc[t], 0, 0, 0);
    }
  }

#pragma unroll
  for (int u = 0; u < 4; ++u) {
    float b0v = ldf(bmsg, wf, u * 32 + col);        // ch of tile 2u  : 32u+col
    float b1v = ldf(bmsg, wf, u * 32 + 16 + col);   // ch of tile 2u+1: 32u+16+col
#pragma unroll
    for (int r = 0; r < 4; ++r) {
      uint pk = (uint)f2bf(acc[2 * u][r] + b0v) | ((uint)f2bf(acc[2 * u + 1][r] + b1v) << 16);
      ybf[(uint)(n0 + g * 4 + r) * 64u + (uint)(u * 16 + col)] = pk;
    }
  }
}

// f32 fallback: canonical ybf pairing (2*lane, 2*lane+1); 2 chunks of 8 rows.
__device__ __forceinline__ void gemm_f32_body(const void* __restrict__ x, int xf,
                                              const void* __restrict__ W, int wf,
                                              const void* __restrict__ b,
                                              uint* __restrict__ ybf,
                                              int wave_n0, int lane, char* ldsc) {
  float* xs = (float*)ldsc;  // [8][128] per-wave 4KB
  for (int c = 0; c < 2; ++c) {
    int n0 = wave_n0 + c * 8;
#pragma unroll
    for (int r = 0; r < NPW; ++r) {
      float2 a = ld2(x, xf, (size_t)(n0 + r) * 64 + lane);
      xs[r * 128 + 2 * lane]     = a.x;
      xs[r * 128 + 2 * lane + 1] = a.y;
    }
    asm volatile("s_waitcnt lgkmcnt(0)" ::: "memory");
    __builtin_amdgcn_sched_barrier(0);
    float acc0[NPW], acc1[NPW];
#pragma unroll
    for (int r = 0; r < NPW; ++r) { acc0[r] = 0.f; acc1[r] = 0.f; }
#pragma unroll 4
    for (int k = 0; k < CH; k += 2) {
      float2 w0 = ld2(W, wf, (size_t)k * 64 + lane);
      float2 w1 = ld2(W, wf, (size_t)(k + 1) * 64 + lane);
#pragma unroll
      for (int r = 0; r < NPW; ++r) {
        float2 a = *(const float2*)&xs[r * 128 + k];
        acc0[r] += a.x * w0.x;
        acc1[r] += a.x * w0.y;
        acc0[r] += a.y * w1.x;
        acc1[r] += a.y * w1.y;
      }
    }
    float2 bb = ld2(b, wf, lane);
#pragma unroll
    for (int r = 0; r < NPW; ++r) {
      uint pk = (uint)f2bf(acc0[r] + bb.x) | ((uint)f2bf(acc1[r] + bb.y) << 16);
      ybf[(uint)(n0 + r) * 64u + (uint)lane] = pk;
    }
  }
}

__global__ __launch_bounds__(256) void gemm_node(const void* __restrict__ x, int x_sel,
                                                 const ushort* __restrict__ wshm,
                                                 const void* __restrict__ W,
                                                 const void* __restrict__ b,
                                                 const int* __restrict__ flags,
                                                 uint* __restrict__ ybf) {
  __shared__ char lds[16384];  // 4 KB per wave
  const int wave = threadIdx.x >> 6;
  const int lane = threadIdx.x & 63;
  const int wid = blockIdx.x * 4 + wave;
  if (wid >= N_NODES / 16) return;
  const int n0 = wid * 16;
  const int xf = resolve_f32(x_sel, flags), wf = flags[3];
  const int MAP = flags[4];
  char* myl = lds + wave * 4096;
  if (MAP == 0)      gemm_mfma_body<0>(x, xf, wshm, b, wf, ybf, n0, lane, myl);
  else if (MAP == 1) gemm_mfma_body<1>(x, xf, wshm, b, wf, ybf, n0, lane, myl);
  else               gemm_f32_body(x, xf, W, wf, b, ybf, n0, lane, myl);
}

// ---------------------------------------------------------------- CSR aggregation with edge-MFMA, 8 nodes/wave:
// R9 was latency-bound at ~1.45 batches/wave: full W_e prologue + serial dep
// chain per wave, no loop ILP (occupancy 28%, VALU 42%). Now each wave owns 8
// consecutive nodes: prologue amortized 8x, ~12 batches/wave give the scheduler
// a loop to pipeline. Tail slots are masked by construction instead of valid*:
// A-row zeroed (zf=0) and src pointed at the zeroed ybf row N_NODES (y=0), so
// the invalid contribution is exactly +0.0 -- bit-identical to R9's masked sum.
template <int MAP>
__device__ __forceinline__ void agg_mfma_body(const uint* __restrict__ ybf,
                                              const void* __restrict__ ea, int ef,
                                              const ushort* __restrict__ wze,
                                              const int* __restrict__ rowptr,
                                              const int2* __restrict__ sev,
                                              float* __restrict__ agg,
                                              int n0, int lane) {
  const int col = lane & 15, g = lane >> 4;
  short8v bfr[8];
#pragma unroll
  for (int t = 0; t < 8; ++t)
    bfr[t] = *(const short8v*)(wze + ((size_t)t * 512 + lane * 8));

  for (int ni = 0; ni < 8; ++ni) {
    const int n = n0 + ni;
    const int beg = rowptr[n], end = rowptr[n + 1];
    f32x4 acc[8];
#pragma unroll
    for (int t = 0; t < 8; ++t) acc[t] = (f32x4){0.f, 0.f, 0.f, 0.f};

    for (int j0 = beg; j0 < end; j0 += 16) {
      int jr = j0 + col;              // this lane stages A-row 'col'
      uint amask = (jr < end) ? 0xFFFFFFFFu : 0u;
      if (jr > end - 1) jr = end - 1;
      int2 p = sev[jr];
      int e = p.y;
      short8v a;
      if (MAP == 1) {                 // k = 8g+j: dims 8g..8g+7 (g<2), zero g>=2
        if (g < 2) {
          float4 qa = ld4(ea, ef, (size_t)e * 4 + 2 * g);
          float4 qb = ld4(ea, ef, (size_t)e * 4 + 2 * g + 1);
          uint4 pk;
          pk.x = ((uint)f2bf(qa.x) | ((uint)f2bf(qa.y) << 16)) & amask;
          pk.y = ((uint)f2bf(qa.z) | ((uint)f2bf(qa.w) << 16)) & amask;
          pk.z = ((uint)f2bf(qb.x) | ((uint)f2bf(qb.y) << 16)) & amask;
          pk.w = ((uint)f2bf(qb.z) | ((uint)f2bf(qb.w) << 16)) & amask;
          *(uint4*)&a = pk;
        } else {
          *(uint4*)&a = make_uint4(0, 0, 0, 0);
        }
      } else {                        // MAP0: j<4 -> k=4g+j (real); j>=4 -> k>=16 zero
        float4 q = ld4(ea, ef, (size_t)e * 4 + g);
        uint4 pk;
        pk.x = ((uint)f2bf(q.x) | ((uint)f2bf(q.y) << 16)) & amask;
        pk.y = ((uint)f2bf(q.z) | ((uint)f2bf(q.w) << 16)) & amask;
        pk.z = 0; pk.w = 0;
        *(uint4*)&a = pk;
      }
      f32x4 zz = {0.f, 0.f, 0.f, 0.f};
      f32x4 zf[8];
#pragma unroll
      for (int t = 0; t < 8; ++t)
        zf[t] = __builtin_amdgcn_mfma_f32_16x16x32_bf16(a, bfr[t], zz, 0, 0, 0);

      int myS = p.x;                  // src of edge slot 'col' (lanes 0..15 authoritative)
#pragma unroll
      for (int r = 0; r < 4; ++r) {
        int slot = g * 4 + r;
        int s = __shfl(myS, slot);    // lane 'slot' holds sev[j0+slot]
        if (j0 + slot >= end) s = N_NODES;  // zero row -> contribution +0.0
        uint yb = (uint)s * 64u + (uint)col;
#pragma unroll
        for (int u = 0; u < 4; ++u) {
          uint yu = ybf[yb + (uint)u * 16u];
          float lo = bf2f((ushort)(yu & 0xFFFF));
          float hi = bf2f((ushort)(yu >> 16));
          acc[2 * u][r]     += fmaxf(lo + zf[2 * u][r], 0.f);
          acc[2 * u + 1][r] += fmaxf(hi + zf[2 * u + 1][r], 0.f);
        }
      }
    }
    float part[8];
#pragma unroll
    for (int t = 0; t < 8; ++t) {
      part[t] = (acc[t][0] + acc[t][1]) + (acc[t][2] + acc[t][3]);
      part[t] += __shfl_xor(part[t], 16);
      part[t] += __shfl_xor(part[t], 32);  // all g-replicas now hold full sums
    }
    agg[(size_t)n * CH + (size_t)(2 * g) * 16 + col]     = part[2 * g];
    agg[(size_t)n * CH + (size_t)(2 * g + 1) * 16 + col] = part[2 * g + 1];
  }
}

// Scalar fallback (MAP==2): R7 body, canonical channel pairing, 8 nodes/wave.
__device__ __forceinline__ void agg_f32_body(const uint* __restrict__ ybf,
                                             const void* __restrict__ ea, int ef,
                                             const void* __restrict__ W, int wf,
                                             const int* __restrict__ rowptr,
                                             const int2* __restrict__ sev,
                                             float* __restrict__ agg,
                                             int n0, int lane) {
  const int c0 = 2 * lane, c1 = c0 + 1;
  float wex[EDGE_DIM], wey[EDGE_DIM];
#pragma unroll
  for (int k = 0; k < EDGE_DIM; ++k) {
    wex[k] = ldf(W, wf, (size_t)(CH + k) * CH + c0);
    wey[k] = ldf(W, wf, (size_t)(CH + k) * CH + c1);
  }
  for (int ni = 0; ni < 8; ++ni) {
    const int n = n0 + ni;
    const int beg = rowptr[n], end = rowptr[n + 1];
    float acc0 = 0.f, acc1 = 0.f;
    for (int j = beg; j < end; ++j) {
      int2 p = sev[j];
      int s = __builtin_amdgcn_readfirstlane(p.x), e = __builtin_amdgcn_readfirstlane(p.y);
      uint yu = ybf[(size_t)s * 64 + lane];
      float4 q0 = ld4(ea, ef, (size_t)e * 4 + 0);
      float4 q1 = ld4(ea, ef, (size_t)e * 4 + 1);
      float4 q2 = ld4(ea, ef, (size_t)e * 4 + 2);
      float4 q3 = ld4(ea, ef, (size_t)e * 4 + 3);
      float av[16] = {q0.x, q0.y, q0.z, q0.w, q1.x, q1.y, q1.z, q1.w,
                      q2.x, q2.y, q2.z, q2.w, q3.x, q3.y, q3.z, q3.w};
      float z0 = 0.f, z1 = 0.f;
#pragma unroll
      for (int k = 0; k < EDGE_DIM; ++k) {
        z0 += av[k] * wex[k];
        z1 += av[k] * wey[k];
      }
      acc0 += fmaxf(bf2f((ushort)(yu & 0xFFFF)) + z0, 0.f);
      acc1 += fmaxf(bf2f((ushort)(yu >> 16)) + z1, 0.f);
    }
    agg[(size_t)n * CH + c0] = acc0;
    agg[(size_t)n * CH + c1] = acc1;
  }
}

__global__ __launch_bounds__(256) void agg_csr(const uint* __restrict__ ybf,
                                               const void* __restrict__ ea,
                                               const ushort* __restrict__ wze,
                                               const void* __restrict__ W,
                                               const int* __restrict__ rowptr,
                                               const int2* __restrict__ sev,
                                               const int* __restrict__ flags,
                                               float* __restrict__ agg) {
  const int wave = threadIdx.x >> 6;
  const int lane = threadIdx.x & 63;
  const int n0 = (blockIdx.x * 4 + wave) * 8;  // grid = N/32 exactly
  const int ef = flags[2], wf = flags[3], MAP = flags[4];
  if (MAP == 0)      agg_mfma_body<0>(ybf, ea, ef, wze, rowptr, sev, agg, n0, lane);
  else if (MAP == 1) agg_mfma_body<1>(ybf, ea, ef, wze, rowptr, sev, agg, n0, lane);
  else               agg_f32_body(ybf, ea, ef, W, wf, rowptr, sev, agg, n0, lane);
}

// ---------------------------------------------------------------- update GEMM on MFMA + fused norm (R6, unchanged)
template <int MAP>
__device__ __forceinline__ void upd_mfma_body(const void* __restrict__ x, int xf,
                                              const float* __restrict__ agg,
                                              const int* __restrict__ rowptr,
                                              const ushort* __restrict__ wsh,
                                              const void* __restrict__ bupd, int wf,
                                              const void* __restrict__ bias,
                                              float* __restrict__ out, int relu,
                                              int n0, int lane, char* lds) {
  const int srow = lane >> 2;
  const int q = lane & 3;
  {
    int c = rowptr[n0 + srow + 1] - rowptr[n0 + srow];
    float inv = 1.f / (float)(c > 1 ? c : 1);
    uint sw = (uint)((srow & 7) << 4);
#pragma unroll
    for (int i = 0; i < 8; ++i) {
      int qi = q + 4 * i;
      float4 v = ld4(x, xf, (size_t)(n0 + srow) * 32 + qi);
      uint2 pk;
      pk.x = (uint)f2bf(v.x) | ((uint)f2bf(v.y) << 16);
      pk.y = (uint)f2bf(v.z) | ((uint)f2bf(v.w) << 16);
      *(uint2*)(lds + (((uint)srow * 512u + (uint)qi * 8u) ^ sw)) = pk;
      float4 w = ((const float4*)agg)[(size_t)(n0 + srow) * 32 + qi];
      uint2 pk2;
      pk2.x = (uint)f2bf(w.x * inv) | ((uint)f2bf(w.y * inv) << 16);
      pk2.y = (uint)f2bf(w.z * inv) | ((uint)f2bf(w.w * inv) << 16);
      *(uint2*)(lds + (((uint)srow * 512u + 256u + (uint)qi * 8u) ^ sw)) = pk2;
    }
  }
  asm volatile("s_waitcnt lgkmcnt(0)" ::: "memory");
  __builtin_amdgcn_sched_barrier(0);

  const int col = lane & 15, g = lane >> 4;
  const int ra = lane & 15;
  const uint asw = (uint)((ra & 7) << 4);
  f32x4 acc[8];
#pragma unroll
  for (int t = 0; t < 8; ++t) acc[t] = (f32x4){0.f, 0.f, 0.f, 0.f};

#pragma unroll
  for (int step = 0; step < 8; ++step) {
    short8v a;
    if (MAP) {
      uint byte = (uint)ra * 512u + (uint)(step * 32 + 8 * g) * 2u;
      *(uint4*)&a = *(const uint4*)(lds + (byte ^ asw));
    } else {
      uint b0 = (uint)ra * 512u + (uint)(step * 32 + 4 * g) * 2u;
      uint b1 = b0 + 32u;
      uint2 lo = *(const uint2*)(lds + (b0 ^ asw));
      uint2 hi = *(const uint2*)(lds + (b1 ^ asw));
      uint4 pk = make_uint4(lo.x, lo.y, hi.x, hi.y);
      *(uint4*)&a = pk;
    }
#pragma unroll
    for (int t = 0; t < 8; ++t) {
      short8v b = *(const short8v*)(wsh + ((size_t)(t * 8 + step) * 512 + lane * 8));
      acc[t] = __builtin_amdgcn_mfma_f32_16x16x32_bf16(a, b, acc[t], 0, 0, 0);
    }
  }

  float bu[8], bi[8];
#pragma unroll
  for (int t = 0; t < 8; ++t) {
    bu[t] = ldf(bupd, wf, t * 16 + col);
    bi[t] = ldf(bias, wf, t * 16 + col);
  }
  float raw[8][4];
  float ss[4] = {0.f, 0.f, 0.f, 0.f};
#pragma unroll
  for (int t = 0; t < 8; ++t)
#pragma unroll
    for (int r = 0; r < 4; ++r) {
      float v = acc[t][r] + bu[t];
      raw[t][r] = v;
      ss[r] += v * v;
    }
#pragma unroll
  for (int r = 0; r < 4; ++r)
#pragma unroll
    for (int o = 1; o < 16; o <<= 1) ss[r] += __shfl_xor(ss[r], o);
#pragma unroll
  for (int r = 0; r < 4; ++r) {
    float inv = 1.0f / fmaxf(sqrtf(ss[r]), 1e-12f);
    int row = g * 4 + r;
#pragma unroll
    for (int t = 0; t < 8; ++t) {
      float o = raw[t][r] * inv + bi[t];
      if (relu) o = fmaxf(o, 0.f);
      out[(size_t)(n0 + row) * CH + t * 16 + col] = o;
    }
  }
}

__device__ __forceinline__ void upd_f32_body(const void* __restrict__ x, int xf,
                                             const float* __restrict__ agg,
                                             const int* __restrict__ rowptr,
                                             const void* __restrict__ W, int wf,
                                             const void* __restrict__ bupd,
                                             const void* __restrict__ bias,
                                             float* __restrict__ out, int relu,
                                             int wave_n0, int lane, char* ldsc) {
  float* xs = (float*)ldsc;  // [8][256] f32 = 8 KB per-wave slice
  for (int c = 0; c < 2; ++c) {
    int n0 = wave_n0 + c * 8;
#pragma unroll
    for (int r = 0; r < NPW; ++r) {
      int n = n0 + r;
      float2 a = ld2(x, xf, (size_t)n * 64 + lane);
      xs[r * 256 + 2 * lane]     = a.x;
      xs[r * 256 + 2 * lane + 1] = a.y;
      int cd = rowptr[n + 1] - rowptr[n];
      float inv = 1.f / (float)(cd > 1 ? cd : 1);
      xs[r * 256 + CH + 2 * lane]     = agg[(size_t)n * CH + 2 * lane] * inv;
      xs[r * 256 + CH + 2 * lane + 1] = agg[(size_t)n * CH + 2 * lane + 1] * inv;
    }
    asm volatile("s_waitcnt lgkmcnt(0)" ::: "memory");
    __builtin_amdgcn_sched_barrier(0);

    float acc0[NPW], acc1[NPW];
#pragma unroll
    for (int r = 0; r < NPW; ++r) { acc0[r] = 0.f; acc1[r] = 0.f; }
#pragma unroll 4
    for (int k = 0; k < KUPD; k += 2) {
      float2 w0 = ld2(W, wf, (size_t)k * 64 + lane);
      float2 w1 = ld2(W, wf, (size_t)(k + 1) * 64 + lane);
#pragma unroll
      for (int r = 0; r < NPW; ++r) {
        float2 a = *(const float2*)&xs[r * 256 + k];
        acc0[r] += a.x * w0.x;
        acc1[r] += a.x * w0.y;
        acc0[r] += a.y * w1.x;
        acc1[r] += a.y * w1.y;
      }
    }
    float2 b  = ld2(bupd, wf, lane);
    float2 bi = ld2(bias, wf, lane);
#pragma unroll
    for (int r = 0; r < NPW; ++r) {
      float r0 = acc0[r] + b.x;
      float r1 = acc1[r] + b.y;
      float sq = r0 * r0 + r1 * r1;
#pragma unroll
      for (int o = 32; o; o >>= 1) sq += __shfl_xor(sq, o);
      float innv = 1.0f / fmaxf(sqrtf(sq), 1e-12f);
      float o0 = r0 * innv + bi.x;
      float o1 = r1 * innv + bi.y;
      if (relu) { o0 = fmaxf(o0, 0.f); o1 = fmaxf(o1, 0.f); }
      size_t n = (size_t)(n0 + r);
      out[n * CH + 2 * lane]     = o0;
      out[n * CH + 2 * lane + 1] = o1;
    }
  }
}

__global__ __launch_bounds__(256) void upd_fused(const void* __restrict__ x, int x_sel,
                                                 const float* __restrict__ agg,
                                                 const int* __restrict__ rowptr,
                                                 const ushort* __restrict__ wsh,
                                                 const void* __restrict__ W,
                                                 const void* __restrict__ bupd,
                                                 const void* __restrict__ bias,
                                                 const int* __restrict__ flags,
                                                 float* __restrict__ out,
                                                 int relu) {
  __shared__ char lds[32768];  // 8 KB per wave
  const int wave = threadIdx.x >> 6;
  const int lane = threadIdx.x & 63;
  const int wid = blockIdx.x * 4 + wave;
  if (wid >= N_NODES / 16) return;
  const int n0 = wid * 16;
  const int xf = resolve_f32(x_sel, flags), wf = flags[3];
  const int MAP = flags[4];
  char* myl = lds + wave * 8192;
  if (MAP == 0)
    upd_mfma_body<0>(x, xf, agg, rowptr, wsh, bupd, wf, bias, out, relu, n0, lane, myl);
  else if (MAP == 1)
    upd_mfma_body<1>(x, xf, agg, rowptr, wsh, bupd, wf, bias, out, relu, n0, lane, myl);
  else
    upd_f32_body(x, xf, agg, rowptr, W, wf, bupd, bias, out, relu, n0, lane, myl);
}

// ---------------------------------------------------------------- host
extern "C" void kernel_launch(void* const* d_in, const int* in_sizes, int n_in,
                              void* d_out, int out_size, void* d_ws, size_t ws_size,
                              hipStream_t stream) {
  const void* x   = d_in[0];
  const int*  ei  = (const int*)d_in[1];
  const void* ea  = d_in[2];
  const void* wm1 = d_in[3];
  const void* bm1 = d_in[4];
  const void* wu1 = d_in[5];
  const void* bu1 = d_in[6];
  const void* bi1 = d_in[7];
  const void* wm2 = d_in[8];
  const void* bm2 = d_in[9];
  const void* wu2 = d_in[10];
  const void* bu2 = d_in[11];
  const void* bi2 = d_in[12];
  float* out = (float*)d_out;

  char* base = (char*)d_ws;
  size_t off = 0;
  auto alloc = [&](size_t b) { size_t o = off; off += (b + 255) & ~(size_t)255; return o; };
  size_t flags_o = alloc(32);
  size_t cnt_o   = alloc((size_t)N_NODES * 4);
  size_t fill_o  = alloc((size_t)N_NODES * 4);
  size_t zero_end = off;                       // memset covers flags|cnt|fill only
  size_t rowp_o  = alloc((size_t)(N_NODES + 1) * 4);
  size_t sev_o   = alloc((size_t)N_EDGES * 8);
  size_t agg_o   = alloc((size_t)N_NODES * CH * 4);
  size_t y_o     = alloc((size_t)(N_NODES + 1) * CH * 2);  // packed bf16 + zero row
  size_t wsh1_o  = alloc((size_t)4096 * 8 * 2);       // upd W1 frags, 64 KB
  size_t wsh2_o  = alloc((size_t)4096 * 8 * 2);       // upd W2 frags
  size_t wshm1_o = alloc((size_t)2048 * 8 * 2);       // msg W1[0:128] frags, 32 KB
  size_t wshm2_o = alloc((size_t)2048 * 8 * 2);       // msg W2[0:128] frags
  size_t wze1_o  = alloc((size_t)512 * 8 * 2);        // W_e1 K=32-padded frags, 8 KB
  size_t wze2_o  = alloc((size_t)512 * 8 * 2);        // W_e2
  (void)ws_size; (void)n_in; (void)in_sizes; (void)out_size;

  int*    flags = (int*)(base + flags_o);
  int*    cntp  = (int*)(base + cnt_o);
  int*    fillp = (int*)(base + fill_o);
  int*    rowp  = (int*)(base + rowp_o);
  int2*   sevp  = (int2*)(base + sev_o);
  float*  aggp  = (float*)(base + agg_o);
  uint*   ybfp  = (uint*)(base + y_o);
  ushort* wsh1  = (ushort*)(base + wsh1_o);
  ushort* wsh2  = (ushort*)(base + wsh2_o);
  ushort* wshm1 = (ushort*)(base + wshm1_o);
  ushort* wshm2 = (ushort*)(base + wshm2_o);
  ushort* wze1  = (ushort*)(base + wze1_o);
  ushort* wze2  = (ushort*)(base + wze2_o);
  float*  hp    = out;                  // layer-1 output (f32) lives in d_out

  hipMemsetAsync(base, 0, zero_end, stream);
  detect_probe<<<1, 256, 0, stream>>>(ei, (const ushort*)x, (const ushort*)ea,
                                      (const ushort*)wm1, flags);
  count_kernel<<<(N_EDGES + 255) / 256, 256, 0, stream>>>(ei, flags, cntp);
  scan_kernel<<<1, 1024, 0, stream>>>(cntp, rowp);
  scatter_kernel<<<(N_EDGES + 255) / 256, 256, 0, stream>>>(ei, flags, rowp, fillp, sevp);
  wshuf_all<<<53, 256, 0, stream>>>(wu1, wu2, wm1, wm2, flags,
                                    wsh1, wsh2, wshm1, wshm2, wze1, wze2, ybfp);

  const int agrid = N_NODES / 32;            // 3125 (4 waves x 8 nodes)
  const int wgrid = (N_NODES / 16 + 3) / 4;  // 1563 (4 waves x 16 rows)

  // ---- layer 1
  gemm_node<<<wgrid, 256, 0, stream>>>(x, 1, wshm1, wm1, bm1, flags, ybfp);
  agg_csr<<<agrid, 256, 0, stream>>>(ybfp, ea, wze1, wm1, rowp, sevp, flags, aggp);
  upd_fused<<<wgrid, 256, 0, stream>>>(x, 1, aggp, rowp, wsh1, wu1, bu1, bi1, flags, hp, 1);

  // ---- layer 2 (h is f32 in d_out -> x_sel=2 forces f32)
  gemm_node<<<wgrid, 256, 0, stream>>>(hp, 2, wshm2, wm2, bm2, flags, ybfp);
  agg_csr<<<agrid, 256, 0, stream>>>(ybfp, ea, wze2, wm2, rowp, sevp, flags, aggp);
  upd_fused<<<wgrid, 256, 0, stream>>>(hp, 2, aggp, rowp, wsh2, wu2, bu2, bi2, flags, out, 0);
}